// Round 1
// baseline (1215.425 us; speedup 1.0000x reference)
//
#include <hip/hip_runtime.h>
#include <stdint.h>

#define Bq 256
#define Sq 49
#define Dq 1024
#define Hq 2
#define HDq 512
#define Mq (Bq*Sq)        // 12544
#define KHEADq (Sq*Dq)    // 50176

typedef unsigned short u16;
typedef short bf16x8 __attribute__((ext_vector_type(8)));
typedef float f32x4 __attribute__((ext_vector_type(4)));

__device__ inline u16 f2bf(float f){
  union { float f; uint32_t u; } c; c.f = f;
  uint32_t r = c.u + 0x7FFFu + ((c.u >> 16) & 1u);
  return (u16)(r >> 16);
}

#define GLOAD_LDS16(gp, lp) \
  __builtin_amdgcn_global_load_lds((__attribute__((address_space(1))) void*)(gp), \
                                   (__attribute__((address_space(3))) void*)(lp), 16, 0, 0)

// h[b*49+s][c] = x[b][c][s] + pos[s][c]
__global__ __launch_bounds__(256) void prep_kernel(const float* __restrict__ x,
    const float* __restrict__ pos, float* __restrict__ h){
  int idx = blockIdx.x*256 + threadIdx.x;
  int b = idx / (Sq*Dq);
  int r = idx - b*(Sq*Dq);
  int s = r >> 10;
  int c = r & 1023;
  h[idx] = x[(size_t)b*(Dq*Sq) + c*Sq + s] + pos[s*Dq + c];
}

// LayerNorm over D=1024, one wave per row, bf16 output
__global__ __launch_bounds__(256) void ln_kernel(const float* __restrict__ hin,
    const float* __restrict__ sc, const float* __restrict__ bi, u16* __restrict__ outp){
  int wave = threadIdx.x >> 6, lane = threadIdx.x & 63;
  int row = blockIdx.x*4 + wave;
  const float* p = hin + (size_t)row*Dq + lane*16;
  float v[16];
  #pragma unroll
  for(int i=0;i<4;i++){
    f32x4 t = *(const f32x4*)(p + i*4);
    v[4*i]=t[0]; v[4*i+1]=t[1]; v[4*i+2]=t[2]; v[4*i+3]=t[3];
  }
  float s=0.f, sq=0.f;
  #pragma unroll
  for(int i=0;i<16;i++){ s += v[i]; sq += v[i]*v[i]; }
  #pragma unroll
  for(int o=32;o>=1;o>>=1){ s += __shfl_xor(s,o); sq += __shfl_xor(sq,o); }
  float mean = s * (1.f/Dq);
  float var  = sq * (1.f/Dq) - mean*mean;
  float rs = rsqrtf(var + 1e-5f);
  int c0 = lane*16;
  uint32_t w[8];
  #pragma unroll
  for(int i=0;i<8;i++){
    u16 lo = f2bf((v[2*i]   - mean)*rs*sc[c0+2*i]   + bi[c0+2*i]);
    u16 hi = f2bf((v[2*i+1] - mean)*rs*sc[c0+2*i+1] + bi[c0+2*i+1]);
    w[i] = (uint32_t)lo | ((uint32_t)hi << 16);
  }
  uint4* ob = (uint4*)(outp + (size_t)row*Dq + c0);
  ob[0] = make_uint4(w[0],w[1],w[2],w[3]);
  ob[1] = make_uint4(w[4],w[5],w[6],w[7]);
}

// (K,N) f32 row-major -> (N,K) bf16 row-major
__global__ void transp_cvt(const float* __restrict__ in, u16* __restrict__ outp, int K, int N){
  __shared__ float t[32][33];
  int k0 = blockIdx.x*32, n0 = blockIdx.y*32;
  int tx = threadIdx.x, ty = threadIdx.y;
  #pragma unroll
  for(int i=0;i<4;i++) t[ty+8*i][tx] = in[(size_t)(k0+ty+8*i)*N + n0+tx];
  __syncthreads();
  #pragma unroll
  for(int i=0;i<4;i++) outp[(size_t)(n0+ty+8*i)*K + k0+tx] = f2bf(t[tx][ty+8*i]);
}

// NT GEMM: C[m][n] = sum_k A[m][k]*Bt[n][k], A/Bt bf16 K-contiguous.
// 128x128 tile, BK=32, 4 waves (2x2), 4x4 16x16x32 frags per wave.
// EPI: 0 = bf16 out; 1 = f32 out = resid + acc (+bias); 2 = bf16 out = gelu(acc+bias)
template<int EPI>
__global__ __launch_bounds__(256) void gemm_nt(
    const u16* __restrict__ A, int lda,
    const u16* __restrict__ Bt, int ldb, int klen,
    void* __restrict__ Cout, const float* __restrict__ resid,
    const float* __restrict__ bias, int ldc)
{
  __shared__ u16 sA[128*32];
  __shared__ u16 sB[128*32];
  int tid = threadIdx.x, lane = tid & 63;
  int wave = tid >> 6;
  int wm = wave >> 1, wn = wave & 1;
  int m0 = blockIdx.y * 128, n0 = blockIdx.x * 128;
  size_t abase = (size_t)m0 * lda;
  size_t bbase = (size_t)n0 * ldb;
  f32x4 zero4 = {0.f,0.f,0.f,0.f};
  f32x4 acc[4][4];
  #pragma unroll
  for(int i=0;i<4;i++)
    #pragma unroll
    for(int j=0;j<4;j++) acc[i][j] = zero4;
  int nk = klen >> 5;
  for(int kt=0; kt<nk; kt++){
    #pragma unroll
    for(int c=0;c<2;c++){
      int s2 = c*256 + tid;
      GLOAD_LDS16(A + abase + (size_t)(s2>>2)*lda + kt*32 + (s2&3)*8, &sA[s2*8]);
    }
    #pragma unroll
    for(int c=0;c<2;c++){
      int s2 = c*256 + tid;
      GLOAD_LDS16(Bt + bbase + (size_t)(s2>>2)*ldb + kt*32 + (s2&3)*8, &sB[s2*8]);
    }
    __syncthreads();
    bf16x8 af[4], bfr[4];
    #pragma unroll
    for(int f=0;f<4;f++)
      af[f] = *(const bf16x8*)&sA[(wm*64 + f*16 + (lane&15))*32 + (lane>>4)*8];
    #pragma unroll
    for(int f=0;f<4;f++)
      bfr[f] = *(const bf16x8*)&sB[(wn*64 + f*16 + (lane&15))*32 + (lane>>4)*8];
    #pragma unroll
    for(int i=0;i<4;i++)
      #pragma unroll
      for(int j=0;j<4;j++)
        acc[i][j] = __builtin_amdgcn_mfma_f32_16x16x32_bf16(af[i], bfr[j], acc[i][j], 0,0,0);
    __syncthreads();
  }
  #pragma unroll
  for(int i=0;i<4;i++){
    #pragma unroll
    for(int j=0;j<4;j++){
      #pragma unroll
      for(int r=0;r<4;r++){
        int row = m0 + wm*64 + i*16 + ((lane>>4)<<2) + r;
        int col = n0 + wn*64 + j*16 + (lane&15);
        size_t oidx = (size_t)row*ldc + col;
        float va = acc[i][j][r];
        if constexpr (EPI == 0){
          ((u16*)Cout)[oidx] = f2bf(va);
        } else if constexpr (EPI == 1){
          float bv = bias ? bias[col] : 0.f;
          ((float*)Cout)[oidx] = resid[oidx] + va + bv;
        } else {
          float xg = va + bias[col];
          float tg = tanhf(0.79788456080286536f*(xg + 0.044715f*xg*xg*xg));
          ((u16*)Cout)[oidx] = f2bf(0.5f*xg*(1.f+tg));
        }
      }
    }
  }
}

// Head GEMM: A (256,50176) bf16 K-contig; W (50176,1024) f32 N-contig (converted in-kernel).
// Split-K over blockIdx.z; writes f32 partials [z][256][1024].
__global__ __launch_bounds__(256) void gemm_head(
    const u16* __restrict__ A, const float* __restrict__ W,
    float* __restrict__ parts, int klen)
{
  __shared__ u16 sA[128*32];
  __shared__ float sW[32*128];
  int tid = threadIdx.x, lane = tid & 63;
  int wave = tid >> 6;
  int wm = wave >> 1, wn = wave & 1;
  int m0 = blockIdx.y*128, n0 = blockIdx.x*128;
  int z = blockIdx.z;
  size_t abase = (size_t)m0*KHEADq + (size_t)z*klen;
  size_t wbase = (size_t)z*klen*1024 + n0;
  f32x4 zero4 = {0.f,0.f,0.f,0.f};
  f32x4 acc[4][4];
  #pragma unroll
  for(int i=0;i<4;i++)
    #pragma unroll
    for(int j=0;j<4;j++) acc[i][j] = zero4;
  int nk = klen >> 5;
  for(int kt=0;kt<nk;kt++){
    #pragma unroll
    for(int c=0;c<2;c++){
      int s2 = c*256+tid;
      GLOAD_LDS16(A + abase + (size_t)(s2>>2)*KHEADq + kt*32 + (s2&3)*8, &sA[s2*8]);
    }
    #pragma unroll
    for(int c=0;c<4;c++){
      int s2 = c*256+tid;   // slot: row = s2>>5 (0..31), col4 = (s2&31)*4
      GLOAD_LDS16(W + wbase + (size_t)(kt*32 + (s2>>5))*1024 + (s2&31)*4, &sW[s2*4]);
    }
    __syncthreads();
    bf16x8 af[4], bfr[4];
    #pragma unroll
    for(int f=0;f<4;f++)
      af[f] = *(const bf16x8*)&sA[(wm*64 + f*16 + (lane&15))*32 + (lane>>4)*8];
    #pragma unroll
    for(int f=0;f<4;f++){
      int n = wn*64 + f*16 + (lane&15);
      int kb = (lane>>4)*8;
      bf16x8 bv;
      #pragma unroll
      for(int jj=0;jj<8;jj++) bv[jj] = (short)f2bf(sW[(kb+jj)*128 + n]);
      bfr[f] = bv;
    }
    #pragma unroll
    for(int i=0;i<4;i++)
      #pragma unroll
      for(int j=0;j<4;j++)
        acc[i][j] = __builtin_amdgcn_mfma_f32_16x16x32_bf16(af[i], bfr[j], acc[i][j], 0,0,0);
    __syncthreads();
  }
  #pragma unroll
  for(int i=0;i<4;i++)
    #pragma unroll
    for(int j=0;j<4;j++)
      #pragma unroll
      for(int r=0;r<4;r++){
        int row = m0 + wm*64 + i*16 + ((lane>>4)<<2) + r;
        int col = n0 + wn*64 + j*16 + (lane&15);
        parts[(size_t)z*(Bq*1024) + (size_t)row*1024 + col] = acc[i][j][r];
      }
}

// Fused attention per (b,h): QK^T (MFMA, 49->64 pad) -> softmax -> P*V (MFMA, V read direct).
// ctx written over q buffer (disjoint col ranges per h, same rows as this block's q reads).
__global__ __launch_bounds__(256) void attn_kernel(const u16* __restrict__ q,
    const u16* __restrict__ kk, const u16* __restrict__ vv, u16* __restrict__ ctx)
{
  __shared__ float sS[64][65];
  __shared__ u16 sP[64][64];
  int bh = blockIdx.x;
  int b = bh >> 1, h = bh & 1;
  int tid = threadIdx.x, lane = tid & 63, wave = tid >> 6;
  int l15 = lane & 15, l4 = lane >> 4;
  f32x4 zero4 = {0.f,0.f,0.f,0.f};
  bf16x8 zb = {0,0,0,0,0,0,0,0};
  f32x4 acc[4];
  #pragma unroll
  for(int i=0;i<4;i++) acc[i] = zero4;
  int srow = wave*16 + l15;
  const u16* qp = q + (size_t)(b*Sq + srow)*Dq + h*HDq + l4*8;
  const u16* kbase = kk + (size_t)b*Sq*Dq + h*HDq + l4*8;
  for(int kt=0;kt<16;kt++){
    bf16x8 aq = (srow < Sq) ? *(const bf16x8*)(qp + kt*32) : zb;
    #pragma unroll
    for(int fn=0;fn<4;fn++){
      int s2 = fn*16 + l15;
      bf16x8 bk = (s2 < Sq) ? *(const bf16x8*)(kbase + (size_t)s2*Dq + kt*32) : zb;
      acc[fn] = __builtin_amdgcn_mfma_f32_16x16x32_bf16(aq, bk, acc[fn], 0,0,0);
    }
  }
  const float scale = 0.04419417382415922f; // 1/sqrt(512)
  #pragma unroll
  for(int fn=0;fn<4;fn++)
    #pragma unroll
    for(int r=0;r<4;r++)
      sS[wave*16 + l4*4 + r][fn*16 + l15] = acc[fn][r]*scale;
  __syncthreads();
  if(tid < 64){
    float mx = -1e30f;
    for(int j=0;j<Sq;j++) mx = fmaxf(mx, sS[tid][j]);
    float sum = 0.f;
    for(int j=0;j<Sq;j++){ float e = __expf(sS[tid][j]-mx); sS[tid][j]=e; sum+=e; }
    float inv = 1.f/sum;
    for(int j=0;j<64;j++) sP[tid][j] = (j<Sq)? f2bf(sS[tid][j]*inv) : (u16)0;
  }
  __syncthreads();
  bf16x8 ap[2];
  #pragma unroll
  for(int kt2=0;kt2<2;kt2++)
    ap[kt2] = *(const bf16x8*)&sP[wave*16 + l15][kt2*32 + l4*8];
  const u16* vb = vv + (size_t)b*Sq*Dq + h*HDq + l15;
  u16* cb = ctx + (size_t)b*Sq*Dq + h*HDq;
  for(int fn=0;fn<32;fn++){
    f32x4 c4 = zero4;
    #pragma unroll
    for(int kt2=0;kt2<2;kt2++){
      const u16* vp = vb + fn*16 + (size_t)(kt2*32 + l4*8)*Dq;
      bf16x8 bv;
      #pragma unroll
      for(int jj=0;jj<8;jj++) bv[jj] = (short)vp[(size_t)jj*Dq];
      c4 = __builtin_amdgcn_mfma_f32_16x16x32_bf16(ap[kt2], bv, c4, 0,0,0);
    }
    #pragma unroll
    for(int r=0;r<4;r++){
      int s = wave*16 + l4*4 + r;
      if(s < Sq) cb[(size_t)s*Dq + fn*16 + l15] = f2bf(c4[r]);
    }
  }
}

__global__ __launch_bounds__(256) void head_finalize(const float* __restrict__ parts,
    const float* __restrict__ hb, float* __restrict__ outp){
  int idx = blockIdx.x*256 + threadIdx.x;
  float s = hb[idx & 1023];
  #pragma unroll
  for(int z=0;z<16;z++) s += parts[(size_t)z*(Bq*1024) + idx];
  outp[idx] = fmaxf(s, 0.f);
}

extern "C" void kernel_launch(void* const* d_in, const int* in_sizes, int n_in,
                              void* d_out, int out_size, void* d_ws, size_t ws_size,
                              hipStream_t stream) {
  (void)in_sizes; (void)n_in; (void)out_size;
  const float* x    = (const float*)d_in[0];
  const float* pos  = (const float*)d_in[1];
  const float* ln1s = (const float*)d_in[2];
  const float* ln1b = (const float*)d_in[3];
  const float* wq   = (const float*)d_in[4];
  const float* wk   = (const float*)d_in[5];
  const float* wv   = (const float*)d_in[6];
  const float* wo   = (const float*)d_in[7];
  const float* ln2s = (const float*)d_in[8];
  const float* ln2b = (const float*)d_in[9];
  const float* w1   = (const float*)d_in[10];
  const float* b1   = (const float*)d_in[11];
  const float* w2   = (const float*)d_in[12];
  const float* b2   = (const float*)d_in[13];
  const float* lnfs = (const float*)d_in[14];
  const float* lnfb = (const float*)d_in[15];
  const float* hw   = (const float*)d_in[16];
  const float* hb   = (const float*)d_in[17];
  float* out = (float*)d_out;

  char* ws = (char*)d_ws;
  size_t off = 0;
  auto carve = [&](size_t n) -> char* { char* p = ws + off; off += (n + 255) & ~(size_t)255; return p; };
  float* h    = (float*)carve((size_t)Mq*Dq*4);
  u16*  act0  = (u16*) carve((size_t)Mq*Dq*2);
  u16*  act1  = (u16*) carve((size_t)Mq*Dq*2);
  u16*  qb    = (u16*) carve((size_t)Mq*Dq*2);
  u16*  kb    = (u16*) carve((size_t)Mq*Dq*2);
  u16*  vb    = (u16*) carve((size_t)(Mq+16)*Dq*2);
  u16*  wT    = (u16*) carve((size_t)12*Dq*Dq*2);
  float* parts= (float*)carve((size_t)16*Bq*1024*4);
  if (off > ws_size) return;  // workspace too small -> clean failure (out stays zero)

  // zero v pad rows (read by attention b=255 against P=0; must be finite)
  hipMemsetAsync(vb + (size_t)Mq*Dq, 0, (size_t)16*Dq*2, stream);

  prep_kernel<<<(Mq*Dq)/256, 256, 0, stream>>>(x, pos, h);

  // pre-transpose the 12 layer weights to bf16 (N,K)
  for(int l=0;l<2;l++){
    const float* srcs[6] = { wq + (size_t)l*Dq*Dq, wk + (size_t)l*Dq*Dq, wv + (size_t)l*Dq*Dq,
                             wo + (size_t)l*Dq*Dq, w1 + (size_t)l*Dq*Dq, w2 + (size_t)l*Dq*Dq };
    for(int j=0;j<6;j++)
      transp_cvt<<<dim3(32,32), dim3(32,8), 0, stream>>>(srcs[j], wT + (size_t)(l*6+j)*Dq*Dq, Dq, Dq);
  }

  dim3 gg(8, Mq/128);
  for(int l=0;l<2;l++){
    u16* wqT = wT + (size_t)(l*6+0)*Dq*Dq;
    u16* wkT = wT + (size_t)(l*6+1)*Dq*Dq;
    u16* wvT = wT + (size_t)(l*6+2)*Dq*Dq;
    u16* woT = wT + (size_t)(l*6+3)*Dq*Dq;
    u16* w1T = wT + (size_t)(l*6+4)*Dq*Dq;
    u16* w2T = wT + (size_t)(l*6+5)*Dq*Dq;

    ln_kernel<<<Mq/4, 256, 0, stream>>>(h, ln1s + l*Dq, ln1b + l*Dq, act0);
    gemm_nt<0><<<gg, 256, 0, stream>>>(act0, Dq, wqT, Dq, Dq, qb, nullptr, nullptr, Dq);
    gemm_nt<0><<<gg, 256, 0, stream>>>(act0, Dq, wkT, Dq, Dq, kb, nullptr, nullptr, Dq);
    gemm_nt<0><<<gg, 256, 0, stream>>>(act0, Dq, wvT, Dq, Dq, vb, nullptr, nullptr, Dq);
    attn_kernel<<<Bq*Hq, 256, 0, stream>>>(qb, kb, vb, qb);
    gemm_nt<1><<<gg, 256, 0, stream>>>(qb, Dq, woT, Dq, Dq, h, h, nullptr, Dq);
    ln_kernel<<<Mq/4, 256, 0, stream>>>(h, ln2s + l*Dq, ln2b + l*Dq, act0);
    gemm_nt<2><<<gg, 256, 0, stream>>>(act0, Dq, w1T, Dq, Dq, act1, nullptr, b1 + l*Dq, Dq);
    gemm_nt<1><<<gg, 256, 0, stream>>>(act1, Dq, w2T, Dq, Dq, h, h, b2 + l*Dq, Dq);
  }

  ln_kernel<<<Mq/4, 256, 0, stream>>>(h, lnfs, lnfb, act0);
  gemm_head<<<dim3(8,2,16), 256, 0, stream>>>(act0, hw, parts, KHEADq/16);
  head_finalize<<<1024, 256, 0, stream>>>(parts, hb, out);
}

// Round 2
// 1048.937 us; speedup vs baseline: 1.1587x; 1.1587x over previous
//
#include <hip/hip_runtime.h>
#include <hip/hip_bf16.h>
#include <stdint.h>

#define Bq 256
#define Sq 49
#define Dq 1024
#define Hq 2
#define HDq 512
#define Mq (Bq*Sq)        // 12544
#define KHEADq (Sq*Dq)    // 50176
#define STq 3072          // fused qkv row stride

typedef unsigned short u16;
typedef short bf16x8 __attribute__((ext_vector_type(8)));
typedef float f32x4 __attribute__((ext_vector_type(4)));

__device__ inline u16 f2bf(float f){
  union { float f; uint32_t u; } c; c.f = f;
  uint32_t r = c.u + 0x7FFFu + ((c.u >> 16) & 1u);
  return (u16)(r >> 16);
}

#define GLOAD_LDS16(gp, lp) \
  __builtin_amdgcn_global_load_lds((__attribute__((address_space(1))) void*)(gp), \
                                   (__attribute__((address_space(3))) void*)(lp), 16, 0, 0)

// h[b*49+s][c] = x[b][c][s] + pos[s][c]
__global__ __launch_bounds__(256) void prep_kernel(const float* __restrict__ x,
    const float* __restrict__ pos, float* __restrict__ h){
  int idx = blockIdx.x*256 + threadIdx.x;
  int b = idx / (Sq*Dq);
  int r = idx - b*(Sq*Dq);
  int s = r >> 10;
  int c = r & 1023;
  h[idx] = x[(size_t)b*(Dq*Sq) + c*Sq + s] + pos[s*Dq + c];
}

// LayerNorm over D=1024, one wave per row, bf16 output
__global__ __launch_bounds__(256) void ln_kernel(const float* __restrict__ hin,
    const float* __restrict__ sc, const float* __restrict__ bi, u16* __restrict__ outp){
  int wave = threadIdx.x >> 6, lane = threadIdx.x & 63;
  int row = blockIdx.x*4 + wave;
  const float* p = hin + (size_t)row*Dq + lane*16;
  float v[16];
  #pragma unroll
  for(int i=0;i<4;i++){
    f32x4 t = *(const f32x4*)(p + i*4);
    v[4*i]=t[0]; v[4*i+1]=t[1]; v[4*i+2]=t[2]; v[4*i+3]=t[3];
  }
  float s=0.f, sq=0.f;
  #pragma unroll
  for(int i=0;i<16;i++){ s += v[i]; sq += v[i]*v[i]; }
  #pragma unroll
  for(int o=32;o>=1;o>>=1){ s += __shfl_xor(s,o); sq += __shfl_xor(sq,o); }
  float mean = s * (1.f/Dq);
  float var  = sq * (1.f/Dq) - mean*mean;
  float rs = rsqrtf(var + 1e-5f);
  int c0 = lane*16;
  uint32_t w[8];
  #pragma unroll
  for(int i=0;i<8;i++){
    u16 lo = f2bf((v[2*i]   - mean)*rs*sc[c0+2*i]   + bi[c0+2*i]);
    u16 hi = f2bf((v[2*i+1] - mean)*rs*sc[c0+2*i+1] + bi[c0+2*i+1]);
    w[i] = (uint32_t)lo | ((uint32_t)hi << 16);
  }
  uint4* ob = (uint4*)(outp + (size_t)row*Dq + c0);
  ob[0] = make_uint4(w[0],w[1],w[2],w[3]);
  ob[1] = make_uint4(w[4],w[5],w[6],w[7]);
}

// all 12 layer weights: (K=1024,N=1024) f32 -> (N,K) bf16, slot = blockIdx.z
__global__ void transp_all(const float* __restrict__ wq, const float* __restrict__ wk,
    const float* __restrict__ wv, const float* __restrict__ wo,
    const float* __restrict__ w1, const float* __restrict__ w2, u16* __restrict__ outp){
  __shared__ float t[32][33];
  int slot = blockIdx.z; int l = slot / 6, j = slot - l*6;
  const float* srcs[6] = {wq,wk,wv,wo,w1,w2};
  const float* in = srcs[j] + (size_t)l*Dq*Dq;
  u16* o = outp + (size_t)slot*Dq*Dq;
  int k0 = blockIdx.x*32, n0 = blockIdx.y*32;
  int tx = threadIdx.x, ty = threadIdx.y;
  #pragma unroll
  for(int i=0;i<4;i++) t[ty+8*i][tx] = in[(size_t)(k0+ty+8*i)*Dq + n0+tx];
  __syncthreads();
  #pragma unroll
  for(int i=0;i<4;i++) o[(size_t)(n0+ty+8*i)*Dq + k0+tx] = f2bf(t[tx][ty+8*i]);
}

// NT GEMM: C[m][n] = sum_k A[m][k]*Bt[n][k], A/Bt bf16 K-contiguous.
// 128x128 tile, BK=32, 4 waves (2x2), 4x4 16x16x32 frags per wave. XCD-chunked swizzle.
// EPI: 0 = bf16 out; 1 = f32 out = resid + acc (+bias); 2 = bf16 out = gelu(acc+bias)
template<int EPI>
__global__ __launch_bounds__(256) void gemm_nt(
    const u16* __restrict__ A, int lda,
    const u16* __restrict__ Bt, int ldb, int klen,
    void* __restrict__ Cout, const float* __restrict__ resid,
    const float* __restrict__ bias, int ldc)
{
  __shared__ u16 sA[128*32];
  __shared__ u16 sB[128*32];
  int tid = threadIdx.x, lane = tid & 63;
  int wave = tid >> 6;
  int wm = wave >> 1, wn = wave & 1;
  // XCD-aware chunked swizzle (grid x*y divisible by 8)
  int nwg = gridDim.x*gridDim.y;
  int orig = blockIdx.y*gridDim.x + blockIdx.x;
  int cpx = nwg >> 3;
  int swz = (orig & 7)*cpx + (orig >> 3);
  int bx = swz % gridDim.x, by = swz / gridDim.x;
  int m0 = by * 128, n0 = bx * 128;
  size_t abase = (size_t)m0 * lda;
  size_t bbase = (size_t)n0 * ldb;
  f32x4 zero4 = {0.f,0.f,0.f,0.f};
  f32x4 acc[4][4];
  #pragma unroll
  for(int i=0;i<4;i++)
    #pragma unroll
    for(int j=0;j<4;j++) acc[i][j] = zero4;
  int nk = klen >> 5;
  for(int kt=0; kt<nk; kt++){
    #pragma unroll
    for(int c=0;c<2;c++){
      int s2 = c*256 + tid;
      GLOAD_LDS16(A + abase + (size_t)(s2>>2)*lda + kt*32 + (s2&3)*8, &sA[s2*8]);
    }
    #pragma unroll
    for(int c=0;c<2;c++){
      int s2 = c*256 + tid;
      GLOAD_LDS16(Bt + bbase + (size_t)(s2>>2)*ldb + kt*32 + (s2&3)*8, &sB[s2*8]);
    }
    __syncthreads();
    bf16x8 af[4], bfr[4];
    #pragma unroll
    for(int f=0;f<4;f++)
      af[f] = *(const bf16x8*)&sA[(wm*64 + f*16 + (lane&15))*32 + (lane>>4)*8];
    #pragma unroll
    for(int f=0;f<4;f++)
      bfr[f] = *(const bf16x8*)&sB[(wn*64 + f*16 + (lane&15))*32 + (lane>>4)*8];
    #pragma unroll
    for(int i=0;i<4;i++)
      #pragma unroll
      for(int j=0;j<4;j++)
        acc[i][j] = __builtin_amdgcn_mfma_f32_16x16x32_bf16(af[i], bfr[j], acc[i][j], 0,0,0);
    __syncthreads();
  }
  #pragma unroll
  for(int i=0;i<4;i++){
    #pragma unroll
    for(int j=0;j<4;j++){
      #pragma unroll
      for(int r=0;r<4;r++){
        int row = m0 + wm*64 + i*16 + ((lane>>4)<<2) + r;
        int col = n0 + wn*64 + j*16 + (lane&15);
        size_t oidx = (size_t)row*ldc + col;
        float va = acc[i][j][r];
        if constexpr (EPI == 0){
          ((u16*)Cout)[oidx] = f2bf(va);
        } else if constexpr (EPI == 1){
          float bv = bias ? bias[col] : 0.f;
          ((float*)Cout)[oidx] = resid[oidx] + va + bv;
        } else {
          float xg = va + bias[col];
          float tg = tanhf(0.79788456080286536f*(xg + 0.044715f*xg*xg*xg));
          ((u16*)Cout)[oidx] = f2bf(0.5f*xg*(1.f+tg));
        }
      }
    }
  }
}

// Head GEMM: A (256,50176) bf16 K-contig (act0 reshaped); W (50176,1024) f32 N-contig.
// Split-K by s: blockIdx.z = s (49), klen=1024. W b-frags loaded DIRECTLY from global
// (4x64B segments per instr) and converted in-register. parts[49][256][1024] f32.
__global__ __launch_bounds__(256) void gemm_head(
    const u16* __restrict__ A, const float* __restrict__ W,
    float* __restrict__ parts)
{
  __shared__ u16 sA[128*32];
  int tid = threadIdx.x, lane = tid & 63;
  int wave = tid >> 6;
  int wm = wave >> 1, wn = wave & 1;
  int l15 = lane & 15, l4 = lane >> 4;
  // flatten grid (8,2,49) and XCD-chunk swizzle (784 % 8 == 0)
  int nwg = gridDim.x*gridDim.y*gridDim.z;
  int orig = (blockIdx.z*gridDim.y + blockIdx.y)*gridDim.x + blockIdx.x;
  int cpx = nwg >> 3;
  int swz = (orig & 7)*cpx + (orig >> 3);
  int bx = swz & 7, by = (swz >> 3) & 1, z = swz >> 4;
  int m0 = by*128, n0 = bx*128;
  size_t abase = (size_t)m0*KHEADq + (size_t)z*1024;
  f32x4 zero4 = {0.f,0.f,0.f,0.f};
  f32x4 acc[4][4];
  #pragma unroll
  for(int i=0;i<4;i++)
    #pragma unroll
    for(int j=0;j<4;j++) acc[i][j] = zero4;
  // per-lane W base: k = z*1024 + l4*8 (+ kt*32 + jj), col = n0 + wn*64 + (+f*16) + l15
  const float* wp = W + ((size_t)z*1024 + (size_t)l4*8)*1024 + n0 + wn*64 + l15;
  for(int kt=0;kt<32;kt++){
    #pragma unroll
    for(int c=0;c<2;c++){
      int s2 = c*256+tid;
      GLOAD_LDS16(A + abase + (size_t)(s2>>2)*KHEADq + kt*32 + (s2&3)*8, &sA[s2*8]);
    }
    float wreg[4][8];
    #pragma unroll
    for(int f=0;f<4;f++)
      #pragma unroll
      for(int jj=0;jj<8;jj++)
        wreg[f][jj] = wp[(size_t)(kt*32+jj)*1024 + f*16];
    bf16x8 bfr[4];
    #pragma unroll
    for(int f=0;f<4;f++){
      bf16x8 bv;
      #pragma unroll
      for(int jj=0;jj<8;jj++)
        bv[jj] = __builtin_bit_cast(short, __float2bfloat16(wreg[f][jj]));
      bfr[f] = bv;
    }
    __syncthreads();
    bf16x8 af[4];
    #pragma unroll
    for(int f=0;f<4;f++)
      af[f] = *(const bf16x8*)&sA[(wm*64 + f*16 + l15)*32 + l4*8];
    #pragma unroll
    for(int i=0;i<4;i++)
      #pragma unroll
      for(int j=0;j<4;j++)
        acc[i][j] = __builtin_amdgcn_mfma_f32_16x16x32_bf16(af[i], bfr[j], acc[i][j], 0,0,0);
    __syncthreads();
  }
  #pragma unroll
  for(int i=0;i<4;i++)
    #pragma unroll
    for(int j=0;j<4;j++)
      #pragma unroll
      for(int r=0;r<4;r++){
        int row = m0 + wm*64 + i*16 + (l4<<2) + r;
        int col = n0 + wn*64 + j*16 + l15;
        parts[(size_t)z*(Bq*1024) + (size_t)row*1024 + col] = acc[i][j][r];
      }
}

// Fused attention per (b,h) on the fused qkv buffer (row stride 3072).
// q at col 0, k at 1024, v at 2048; ctx written over q (disjoint per h).
__global__ __launch_bounds__(256) void attn_kernel(u16* __restrict__ qkv)
{
  __shared__ float sS[64][65];
  __shared__ u16 sP[64][64];
  int bh = blockIdx.x;
  int b = bh >> 1, h = bh & 1;
  int tid = threadIdx.x, lane = tid & 63, wave = tid >> 6;
  int l15 = lane & 15, l4 = lane >> 4;
  f32x4 zero4 = {0.f,0.f,0.f,0.f};
  bf16x8 zb = {0,0,0,0,0,0,0,0};
  f32x4 acc[4];
  #pragma unroll
  for(int i=0;i<4;i++) acc[i] = zero4;
  int srow = wave*16 + l15;
  const u16* qp = qkv + (size_t)(b*Sq + srow)*STq + h*HDq + l4*8;
  const u16* kbase = qkv + (size_t)b*Sq*STq + Dq + h*HDq + l4*8;
  for(int kt=0;kt<16;kt++){
    bf16x8 aq = (srow < Sq) ? *(const bf16x8*)(qp + kt*32) : zb;
    #pragma unroll
    for(int fn=0;fn<4;fn++){
      int s2 = fn*16 + l15;
      bf16x8 bk = (s2 < Sq) ? *(const bf16x8*)(kbase + (size_t)s2*STq + kt*32) : zb;
      acc[fn] = __builtin_amdgcn_mfma_f32_16x16x32_bf16(aq, bk, acc[fn], 0,0,0);
    }
  }
  const float scale = 0.04419417382415922f; // 1/sqrt(512)
  #pragma unroll
  for(int fn=0;fn<4;fn++)
    #pragma unroll
    for(int r=0;r<4;r++)
      sS[wave*16 + l4*4 + r][fn*16 + l15] = acc[fn][r]*scale;
  __syncthreads();
  if(tid < 64){
    float mx = -1e30f;
    for(int j=0;j<Sq;j++) mx = fmaxf(mx, sS[tid][j]);
    float sum = 0.f;
    for(int j=0;j<Sq;j++){ float e = __expf(sS[tid][j]-mx); sS[tid][j]=e; sum+=e; }
    float inv = 1.f/sum;
    for(int j=0;j<64;j++) sP[tid][j] = (j<Sq)? f2bf(sS[tid][j]*inv) : (u16)0;
  }
  __syncthreads();
  bf16x8 ap[2];
  #pragma unroll
  for(int kt2=0;kt2<2;kt2++)
    ap[kt2] = *(const bf16x8*)&sP[wave*16 + l15][kt2*32 + l4*8];
  const u16* vbp = qkv + (size_t)b*Sq*STq + 2*Dq + h*HDq + l15;
  u16* cb = qkv + (size_t)b*Sq*STq + h*HDq;
  for(int fn=0;fn<32;fn++){
    f32x4 c4 = zero4;
    #pragma unroll
    for(int kt2=0;kt2<2;kt2++){
      const u16* vp = vbp + fn*16 + (size_t)(kt2*32 + l4*8)*STq;
      bf16x8 bv;
      #pragma unroll
      for(int jj=0;jj<8;jj++) bv[jj] = (short)vp[(size_t)jj*STq];
      c4 = __builtin_amdgcn_mfma_f32_16x16x32_bf16(ap[kt2], bv, c4, 0,0,0);
    }
    #pragma unroll
    for(int r=0;r<4;r++){
      int s = wave*16 + l4*4 + r;
      if(s < Sq) cb[(size_t)s*STq + fn*16 + l15] = f2bf(c4[r]);
    }
  }
}

__global__ __launch_bounds__(256) void head_finalize(const float* __restrict__ parts,
    const float* __restrict__ hb, float* __restrict__ outp){
  int idx = blockIdx.x*256 + threadIdx.x;
  float s = hb[idx & 1023];
  #pragma unroll
  for(int z=0;z<49;z++) s += parts[(size_t)z*(Bq*1024) + idx];
  outp[idx] = fmaxf(s, 0.f);
}

extern "C" void kernel_launch(void* const* d_in, const int* in_sizes, int n_in,
                              void* d_out, int out_size, void* d_ws, size_t ws_size,
                              hipStream_t stream) {
  (void)in_sizes; (void)n_in; (void)out_size;
  const float* x    = (const float*)d_in[0];
  const float* pos  = (const float*)d_in[1];
  const float* ln1s = (const float*)d_in[2];
  const float* ln1b = (const float*)d_in[3];
  const float* wq   = (const float*)d_in[4];
  const float* wk   = (const float*)d_in[5];
  const float* wv   = (const float*)d_in[6];
  const float* wo   = (const float*)d_in[7];
  const float* ln2s = (const float*)d_in[8];
  const float* ln2b = (const float*)d_in[9];
  const float* w1   = (const float*)d_in[10];
  const float* b1   = (const float*)d_in[11];
  const float* w2   = (const float*)d_in[12];
  const float* b2   = (const float*)d_in[13];
  const float* lnfs = (const float*)d_in[14];
  const float* lnfb = (const float*)d_in[15];
  const float* hw   = (const float*)d_in[16];
  const float* hb   = (const float*)d_in[17];
  float* out = (float*)d_out;

  char* ws = (char*)d_ws;
  size_t off = 0;
  auto carve = [&](size_t n) -> char* { char* p = ws + off; off += (n + 255) & ~(size_t)255; return p; };
  float* h    = (float*)carve((size_t)Mq*Dq*4);
  u16*  act0  = (u16*) carve((size_t)Mq*Dq*2);
  u16*  act1  = (u16*) carve((size_t)Mq*Dq*2);
  u16*  qkv   = (u16*) carve((size_t)(Mq+16)*STq*2);
  u16*  wT    = (u16*) carve((size_t)12*Dq*Dq*2);
  float* parts= (float*)qkv;  // head partials alias qkv (dead by head time): 51.4MB <= 77MB
  if (off > ws_size) return;

  // zero qkv pad rows (attention PV reads v-pad rows against P=0; must be finite)
  hipMemsetAsync(qkv + (size_t)Mq*STq, 0, (size_t)16*STq*2, stream);

  prep_kernel<<<(Mq*Dq)/256, 256, 0, stream>>>(x, pos, h);
  transp_all<<<dim3(32,32,12), dim3(32,8), 0, stream>>>(wq, wk, wv, wo, w1, w2, wT);

  dim3 gg(8, Mq/128);
  dim3 gq(24, Mq/128);
  for(int l=0;l<2;l++){
    u16* qkvT = wT + (size_t)(l*6+0)*Dq*Dq;  // q,k,v slots contiguous -> 3072 x 1024
    u16* woT  = wT + (size_t)(l*6+3)*Dq*Dq;
    u16* w1T  = wT + (size_t)(l*6+4)*Dq*Dq;
    u16* w2T  = wT + (size_t)(l*6+5)*Dq*Dq;

    ln_kernel<<<Mq/4, 256, 0, stream>>>(h, ln1s + l*Dq, ln1b + l*Dq, act0);
    gemm_nt<0><<<gq, 256, 0, stream>>>(act0, Dq, qkvT, Dq, Dq, qkv, nullptr, nullptr, STq);
    attn_kernel<<<Bq*Hq, 256, 0, stream>>>(qkv);
    gemm_nt<1><<<gg, 256, 0, stream>>>(qkv, STq, woT, Dq, Dq, h, h, nullptr, Dq);
    ln_kernel<<<Mq/4, 256, 0, stream>>>(h, ln2s + l*Dq, ln2b + l*Dq, act0);
    gemm_nt<2><<<gg, 256, 0, stream>>>(act0, Dq, w1T, Dq, Dq, act1, nullptr, b1 + l*Dq, Dq);
    gemm_nt<1><<<gg, 256, 0, stream>>>(act1, Dq, w2T, Dq, Dq, h, h, b2 + l*Dq, Dq);
  }

  ln_kernel<<<Mq/4, 256, 0, stream>>>(h, lnfs, lnfb, act0);
  gemm_head<<<dim3(8,2,49), 256, 0, stream>>>(act0, hw, parts);
  head_finalize<<<1024, 256, 0, stream>>>(parts, hb, out);
}

// Round 3
// 1003.664 us; speedup vs baseline: 1.2110x; 1.0451x over previous
//
#include <hip/hip_runtime.h>
#include <hip/hip_bf16.h>
#include <stdint.h>

#define Bq 256
#define Sq 49
#define Dq 1024
#define Hq 2
#define HDq 512
#define Mq (Bq*Sq)        // 12544
#define KHEADq (Sq*Dq)    // 50176
#define STq 3072          // fused qkv row stride

typedef unsigned short u16;
typedef short bf16x8 __attribute__((ext_vector_type(8)));
typedef float f32x4 __attribute__((ext_vector_type(4)));

__device__ inline u16 f2bf(float f){
  union { float f; uint32_t u; } c; c.f = f;
  uint32_t r = c.u + 0x7FFFu + ((c.u >> 16) & 1u);
  return (u16)(r >> 16);
}

#define GLOAD_LDS16(gp, lp) \
  __builtin_amdgcn_global_load_lds((__attribute__((address_space(1))) void*)(gp), \
                                   (__attribute__((address_space(3))) void*)(lp), 16, 0, 0)

// h[b*49+s][c] = x[b][c][s] + pos[s][c]  -- LDS transpose for coalescing
__global__ __launch_bounds__(256) void prep_kernel(const float* __restrict__ x,
    const float* __restrict__ pos, float* __restrict__ h){
  __shared__ float t[49*129];
  int b = blockIdx.x, c0 = blockIdx.y*128;
  int tid = threadIdx.x, lane = tid & 63, wave = tid >> 6;
  const float* xb = x + (size_t)b*(Dq*Sq) + (size_t)c0*Sq;
  #pragma unroll
  for(int i=0;i<32;i++){
    int cc = wave + i*4;
    if(lane < Sq) t[lane*129 + cc] = xb[(size_t)cc*Sq + lane];
  }
  __syncthreads();
  #pragma unroll
  for(int p=0;p<25;p++){
    int idx = p*256 + tid;
    int s = idx >> 7, cc = idx & 127;
    if(s < Sq)
      h[((size_t)b*Sq + s)*Dq + c0 + cc] = t[s*129 + cc] + pos[s*Dq + c0 + cc];
  }
}

// LayerNorm over D=1024, one wave per row, bf16 output
__global__ __launch_bounds__(256) void ln_kernel(const float* __restrict__ hin,
    const float* __restrict__ sc, const float* __restrict__ bi, u16* __restrict__ outp){
  int wave = threadIdx.x >> 6, lane = threadIdx.x & 63;
  int row = blockIdx.x*4 + wave;
  const float* p = hin + (size_t)row*Dq + lane*16;
  float v[16];
  #pragma unroll
  for(int i=0;i<4;i++){
    f32x4 t = *(const f32x4*)(p + i*4);
    v[4*i]=t[0]; v[4*i+1]=t[1]; v[4*i+2]=t[2]; v[4*i+3]=t[3];
  }
  float s=0.f, sq=0.f;
  #pragma unroll
  for(int i=0;i<16;i++){ s += v[i]; sq += v[i]*v[i]; }
  #pragma unroll
  for(int o=32;o>=1;o>>=1){ s += __shfl_xor(s,o); sq += __shfl_xor(sq,o); }
  float mean = s * (1.f/Dq);
  float var  = sq * (1.f/Dq) - mean*mean;
  float rs = rsqrtf(var + 1e-5f);
  int c0 = lane*16;
  uint32_t w[8];
  #pragma unroll
  for(int i=0;i<8;i++){
    u16 lo = f2bf((v[2*i]   - mean)*rs*sc[c0+2*i]   + bi[c0+2*i]);
    u16 hi = f2bf((v[2*i+1] - mean)*rs*sc[c0+2*i+1] + bi[c0+2*i+1]);
    w[i] = (uint32_t)lo | ((uint32_t)hi << 16);
  }
  uint4* ob = (uint4*)(outp + (size_t)row*Dq + c0);
  ob[0] = make_uint4(w[0],w[1],w[2],w[3]);
  ob[1] = make_uint4(w[4],w[5],w[6],w[7]);
}

// all 12 layer weights: (K=1024,N=1024) f32 -> (N,K) bf16, slot = blockIdx.z
__global__ void transp_all(const float* __restrict__ wq, const float* __restrict__ wk,
    const float* __restrict__ wv, const float* __restrict__ wo,
    const float* __restrict__ w1, const float* __restrict__ w2, u16* __restrict__ outp){
  __shared__ float t[32][33];
  int slot = blockIdx.z; int l = slot / 6, j = slot - l*6;
  const float* srcs[6] = {wq,wk,wv,wo,w1,w2};
  const float* in = srcs[j] + (size_t)l*Dq*Dq;
  u16* o = outp + (size_t)slot*Dq*Dq;
  int k0 = blockIdx.x*32, n0 = blockIdx.y*32;
  int tx = threadIdx.x, ty = threadIdx.y;
  #pragma unroll
  for(int i=0;i<4;i++) t[ty+8*i][tx] = in[(size_t)(k0+ty+8*i)*Dq + n0+tx];
  __syncthreads();
  #pragma unroll
  for(int i=0;i<4;i++) o[(size_t)(n0+ty+8*i)*Dq + k0+tx] = f2bf(t[tx][ty+8*i]);
}

// NT GEMM: C[m][n] = sum_k A[m][k]*Bt[n][k], A/Bt bf16 K-contiguous.
// 128x128 tile, BK=32, 4 waves (2x2), 4x4 16x16x32 frags per wave. XCD-chunked swizzle.
// EPI: 0 = bf16 out; 1 = f32 out = resid + acc (+bias); 2 = bf16 out = gelu(acc+bias)
// EPI 0/2 use an LDS-staged coalesced store path (full 128B lines, no RFO).
template<int EPI>
__global__ __launch_bounds__(256) void gemm_nt(
    const u16* __restrict__ A, int lda,
    const u16* __restrict__ Bt, int ldb, int klen,
    void* __restrict__ Cout, const float* __restrict__ resid,
    const float* __restrict__ bias, int ldc)
{
  __shared__ u16 sA[128*32];
  __shared__ u16 sB[128*32];
  int tid = threadIdx.x, lane = tid & 63;
  int wave = tid >> 6;
  int wm = wave >> 1, wn = wave & 1;
  int l15 = lane & 15, l4 = lane >> 4;
  // XCD-aware chunked swizzle (grid x*y divisible by 8)
  int nwg = gridDim.x*gridDim.y;
  int orig = blockIdx.y*gridDim.x + blockIdx.x;
  int cpx = nwg >> 3;
  int swz = (orig & 7)*cpx + (orig >> 3);
  int bx = swz % gridDim.x, by = swz / gridDim.x;
  int m0 = by * 128, n0 = bx * 128;
  size_t abase = (size_t)m0 * lda;
  size_t bbase = (size_t)n0 * ldb;
  f32x4 zero4 = {0.f,0.f,0.f,0.f};
  f32x4 acc[4][4];
  #pragma unroll
  for(int i=0;i<4;i++)
    #pragma unroll
    for(int j=0;j<4;j++) acc[i][j] = zero4;
  int nk = klen >> 5;
  for(int kt=0; kt<nk; kt++){
    #pragma unroll
    for(int c=0;c<2;c++){
      int s2 = c*256 + tid;
      GLOAD_LDS16(A + abase + (size_t)(s2>>2)*lda + kt*32 + (s2&3)*8, &sA[s2*8]);
    }
    #pragma unroll
    for(int c=0;c<2;c++){
      int s2 = c*256 + tid;
      GLOAD_LDS16(Bt + bbase + (size_t)(s2>>2)*ldb + kt*32 + (s2&3)*8, &sB[s2*8]);
    }
    __syncthreads();
    bf16x8 af[4], bfr[4];
    #pragma unroll
    for(int f=0;f<4;f++)
      af[f] = *(const bf16x8*)&sA[(wm*64 + f*16 + l15)*32 + l4*8];
    #pragma unroll
    for(int f=0;f<4;f++)
      bfr[f] = *(const bf16x8*)&sB[(wn*64 + f*16 + l15)*32 + l4*8];
    #pragma unroll
    for(int i=0;i<4;i++)
      #pragma unroll
      for(int j=0;j<4;j++)
        acc[i][j] = __builtin_amdgcn_mfma_f32_16x16x32_bf16(af[i], bfr[j], acc[i][j], 0,0,0);
    __syncthreads();
  }
  if constexpr (EPI == 1){
    #pragma unroll
    for(int i=0;i<4;i++)
      #pragma unroll
      for(int j=0;j<4;j++)
        #pragma unroll
        for(int r=0;r<4;r++){
          int row = m0 + wm*64 + i*16 + (l4<<2) + r;
          int col = n0 + wn*64 + j*16 + l15;
          size_t oidx = (size_t)row*ldc + col;
          float bv = bias ? bias[col] : 0.f;
          ((float*)Cout)[oidx] = resid[oidx] + acc[i][j][r] + bv;
        }
  } else {
    // per-wave 2KB staging slot in sA (K-loop done; same-wave DS ops are in-order)
    u16* stg = &sA[wave*1024];
    #pragma unroll
    for(int i=0;i<4;i++){
      #pragma unroll
      for(int j=0;j<4;j++)
        #pragma unroll
        for(int r=0;r<4;r++){
          float va = acc[i][j][r];
          u16 ov;
          if constexpr (EPI == 0){
            ov = f2bf(va);
          } else {
            float xg = va + bias[n0 + wn*64 + j*16 + l15];
            float tg = tanhf(0.79788456080286536f*(xg + 0.044715f*xg*xg*xg));
            ov = f2bf(0.5f*xg*(1.f+tg));
          }
          stg[(l4*4+r)*64 + j*16 + l15] = ov;
        }
      #pragma unroll
      for(int st=0;st<2;st++){
        int u = st*64 + lane;
        int row = u >> 3, c8 = (u & 7)*8;
        bf16x8 v8 = *(const bf16x8*)&stg[row*64 + c8];
        *(bf16x8*)((u16*)Cout + (size_t)(m0+wm*64+i*16+row)*ldc + n0+wn*64+c8) = v8;
      }
    }
  }
}

// Head GEMM: A (256,50176) bf16 K-contig; W (50176,1024) f32 N-contig (reg-converted).
// Split-K by s: z = 0..48, klen=1024. parts[49][256][1024] f32, LDS-staged stores.
__global__ __launch_bounds__(256) void gemm_head(
    const u16* __restrict__ A, const float* __restrict__ W,
    float* __restrict__ parts)
{
  __shared__ u16 sA[128*32];
  __shared__ float sC[4][1024];
  int tid = threadIdx.x, lane = tid & 63;
  int wave = tid >> 6;
  int wm = wave >> 1, wn = wave & 1;
  int l15 = lane & 15, l4 = lane >> 4;
  int nwg = gridDim.x*gridDim.y*gridDim.z;
  int orig = (blockIdx.z*gridDim.y + blockIdx.y)*gridDim.x + blockIdx.x;
  int cpx = nwg >> 3;
  int swz = (orig & 7)*cpx + (orig >> 3);
  int bx = swz & 7, by = (swz >> 3) & 1, z = swz >> 4;
  int m0 = by*128, n0 = bx*128;
  size_t abase = (size_t)m0*KHEADq + (size_t)z*1024;
  f32x4 zero4 = {0.f,0.f,0.f,0.f};
  f32x4 acc[4][4];
  #pragma unroll
  for(int i=0;i<4;i++)
    #pragma unroll
    for(int j=0;j<4;j++) acc[i][j] = zero4;
  const float* wp = W + ((size_t)z*1024 + (size_t)l4*8)*1024 + n0 + wn*64 + l15;
  for(int kt=0;kt<32;kt++){
    #pragma unroll
    for(int c=0;c<2;c++){
      int s2 = c*256+tid;
      GLOAD_LDS16(A + abase + (size_t)(s2>>2)*KHEADq + kt*32 + (s2&3)*8, &sA[s2*8]);
    }
    float wreg[4][8];
    #pragma unroll
    for(int f=0;f<4;f++)
      #pragma unroll
      for(int jj=0;jj<8;jj++)
        wreg[f][jj] = wp[(size_t)(kt*32+jj)*1024 + f*16];
    bf16x8 bfr[4];
    #pragma unroll
    for(int f=0;f<4;f++){
      bf16x8 bv;
      #pragma unroll
      for(int jj=0;jj<8;jj++)
        bv[jj] = __builtin_bit_cast(short, __float2bfloat16(wreg[f][jj]));
      bfr[f] = bv;
    }
    __syncthreads();
    bf16x8 af[4];
    #pragma unroll
    for(int f=0;f<4;f++)
      af[f] = *(const bf16x8*)&sA[(wm*64 + f*16 + l15)*32 + l4*8];
    #pragma unroll
    for(int i=0;i<4;i++)
      #pragma unroll
      for(int j=0;j<4;j++)
        acc[i][j] = __builtin_amdgcn_mfma_f32_16x16x32_bf16(af[i], bfr[j], acc[i][j], 0,0,0);
    __syncthreads();
  }
  float* base = parts + (size_t)z*(Bq*1024);
  #pragma unroll
  for(int i=0;i<4;i++){
    #pragma unroll
    for(int j=0;j<4;j++)
      #pragma unroll
      for(int r=0;r<4;r++)
        sC[wave][(l4*4+r)*64 + j*16 + l15] = acc[i][j][r];
    #pragma unroll
    for(int st=0;st<4;st++){
      int u = st*64 + lane;
      int row = u >> 4, c4 = (u & 15)*4;
      f32x4 v4 = *(const f32x4*)&sC[wave][row*64 + c4];
      *(f32x4*)(base + (size_t)(m0+wm*64+i*16+row)*1024 + n0+wn*64+c4) = v4;
    }
  }
}

// Fused attention per (b,h) on the fused qkv buffer (row stride 3072).
__global__ __launch_bounds__(256) void attn_kernel(u16* __restrict__ qkv)
{
  __shared__ float sS[64][65];
  __shared__ u16 sP[64][64];
  int bh = blockIdx.x;
  int b = bh >> 1, h = bh & 1;
  int tid = threadIdx.x, lane = tid & 63, wave = tid >> 6;
  int l15 = lane & 15, l4 = lane >> 4;
  f32x4 zero4 = {0.f,0.f,0.f,0.f};
  bf16x8 zb = {0,0,0,0,0,0,0,0};
  f32x4 acc[4];
  #pragma unroll
  for(int i=0;i<4;i++) acc[i] = zero4;
  int srow = wave*16 + l15;
  const u16* qp = qkv + (size_t)(b*Sq + srow)*STq + h*HDq + l4*8;
  const u16* kbase = qkv + (size_t)b*Sq*STq + Dq + h*HDq + l4*8;
  for(int kt=0;kt<16;kt++){
    bf16x8 aq = (srow < Sq) ? *(const bf16x8*)(qp + kt*32) : zb;
    #pragma unroll
    for(int fn=0;fn<4;fn++){
      int s2 = fn*16 + l15;
      bf16x8 bk = (s2 < Sq) ? *(const bf16x8*)(kbase + (size_t)s2*STq + kt*32) : zb;
      acc[fn] = __builtin_amdgcn_mfma_f32_16x16x32_bf16(aq, bk, acc[fn], 0,0,0);
    }
  }
  const float scale = 0.04419417382415922f; // 1/sqrt(512)
  #pragma unroll
  for(int fn=0;fn<4;fn++)
    #pragma unroll
    for(int r=0;r<4;r++)
      sS[wave*16 + l4*4 + r][fn*16 + l15] = acc[fn][r]*scale;
  __syncthreads();
  if(tid < 64){
    float mx = -1e30f;
    for(int j=0;j<Sq;j++) mx = fmaxf(mx, sS[tid][j]);
    float sum = 0.f;
    for(int j=0;j<Sq;j++){ float e = __expf(sS[tid][j]-mx); sS[tid][j]=e; sum+=e; }
    float inv = 1.f/sum;
    for(int j=0;j<64;j++) sP[tid][j] = (j<Sq)? f2bf(sS[tid][j]*inv) : (u16)0;
  }
  __syncthreads();
  bf16x8 ap[2];
  #pragma unroll
  for(int kt2=0;kt2<2;kt2++)
    ap[kt2] = *(const bf16x8*)&sP[wave*16 + l15][kt2*32 + l4*8];
  const u16* vbp = qkv + (size_t)b*Sq*STq + 2*Dq + h*HDq + l15;
  u16* cb = qkv + (size_t)b*Sq*STq + h*HDq;
  for(int fn=0;fn<32;fn++){
    f32x4 c4 = zero4;
    #pragma unroll
    for(int kt2=0;kt2<2;kt2++){
      const u16* vp = vbp + fn*16 + (size_t)(kt2*32 + l4*8)*STq;
      bf16x8 bv;
      #pragma unroll
      for(int jj=0;jj<8;jj++) bv[jj] = (short)vp[(size_t)jj*STq];
      c4 = __builtin_amdgcn_mfma_f32_16x16x32_bf16(ap[kt2], bv, c4, 0,0,0);
    }
    #pragma unroll
    for(int r=0;r<4;r++){
      int s = wave*16 + l4*4 + r;
      if(s < Sq) cb[(size_t)s*STq + fn*16 + l15] = f2bf(c4[r]);
    }
  }
}

__global__ __launch_bounds__(256) void head_finalize(const float* __restrict__ parts,
    const float* __restrict__ hb, float* __restrict__ outp){
  int idx = blockIdx.x*256 + threadIdx.x;
  float s = hb[idx & 1023];
  #pragma unroll
  for(int z=0;z<49;z++) s += parts[(size_t)z*(Bq*1024) + idx];
  outp[idx] = fmaxf(s, 0.f);
}

extern "C" void kernel_launch(void* const* d_in, const int* in_sizes, int n_in,
                              void* d_out, int out_size, void* d_ws, size_t ws_size,
                              hipStream_t stream) {
  (void)in_sizes; (void)n_in; (void)out_size;
  const float* x    = (const float*)d_in[0];
  const float* pos  = (const float*)d_in[1];
  const float* ln1s = (const float*)d_in[2];
  const float* ln1b = (const float*)d_in[3];
  const float* wq   = (const float*)d_in[4];
  const float* wk   = (const float*)d_in[5];
  const float* wv   = (const float*)d_in[6];
  const float* wo   = (const float*)d_in[7];
  const float* ln2s = (const float*)d_in[8];
  const float* ln2b = (const float*)d_in[9];
  const float* w1   = (const float*)d_in[10];
  const float* b1   = (const float*)d_in[11];
  const float* w2   = (const float*)d_in[12];
  const float* b2   = (const float*)d_in[13];
  const float* lnfs = (const float*)d_in[14];
  const float* lnfb = (const float*)d_in[15];
  const float* hw   = (const float*)d_in[16];
  const float* hb   = (const float*)d_in[17];
  float* out = (float*)d_out;

  char* ws = (char*)d_ws;
  size_t off = 0;
  auto carve = [&](size_t n) -> char* { char* p = ws + off; off += (n + 255) & ~(size_t)255; return p; };
  float* h    = (float*)carve((size_t)Mq*Dq*4);
  u16*  act0  = (u16*) carve((size_t)Mq*Dq*2);
  u16*  act1  = (u16*) carve((size_t)Mq*Dq*2);
  u16*  qkv   = (u16*) carve((size_t)(Mq+16)*STq*2);
  u16*  wT    = (u16*) carve((size_t)12*Dq*Dq*2);
  float* parts= (float*)qkv;  // head partials alias qkv (dead by head time)
  if (off > ws_size) return;

  // zero qkv pad rows (attention PV reads v-pad rows against P=0; must be finite)
  hipMemsetAsync(qkv + (size_t)Mq*STq, 0, (size_t)16*STq*2, stream);

  prep_kernel<<<dim3(Bq, 8), 256, 0, stream>>>(x, pos, h);
  transp_all<<<dim3(32,32,12), dim3(32,8), 0, stream>>>(wq, wk, wv, wo, w1, w2, wT);

  dim3 gg(8, Mq/128);
  dim3 gq(24, Mq/128);
  for(int l=0;l<2;l++){
    u16* qkvT = wT + (size_t)(l*6+0)*Dq*Dq;  // q,k,v slots contiguous -> 3072 x 1024
    u16* woT  = wT + (size_t)(l*6+3)*Dq*Dq;
    u16* w1T  = wT + (size_t)(l*6+4)*Dq*Dq;
    u16* w2T  = wT + (size_t)(l*6+5)*Dq*Dq;

    ln_kernel<<<Mq/4, 256, 0, stream>>>(h, ln1s + l*Dq, ln1b + l*Dq, act0);
    gemm_nt<0><<<gq, 256, 0, stream>>>(act0, Dq, qkvT, Dq, Dq, qkv, nullptr, nullptr, STq);
    attn_kernel<<<Bq*Hq, 256, 0, stream>>>(qkv);
    gemm_nt<1><<<gg, 256, 0, stream>>>(qkv, STq, woT, Dq, Dq, h, h, nullptr, Dq);
    ln_kernel<<<Mq/4, 256, 0, stream>>>(h, ln2s + l*Dq, ln2b + l*Dq, act0);
    gemm_nt<2><<<gg, 256, 0, stream>>>(act0, Dq, w1T, Dq, Dq, act1, nullptr, b1 + l*Dq, Dq);
    gemm_nt<1><<<gg, 256, 0, stream>>>(act1, Dq, w2T, Dq, Dq, h, h, b2 + l*Dq, Dq);
  }

  ln_kernel<<<Mq/4, 256, 0, stream>>>(h, lnfs, lnfb, act0);
  gemm_head<<<dim3(8,2,49), 256, 0, stream>>>(act0, hw, parts);
  head_finalize<<<1024, 256, 0, stream>>>(parts, hb, out);
}

// Round 4
// 738.120 us; speedup vs baseline: 1.6466x; 1.3598x over previous
//
#include <hip/hip_runtime.h>
#include <hip/hip_bf16.h>
#include <stdint.h>

#define Bq 256
#define Sq 49
#define Dq 1024
#define Hq 2
#define HDq 512
#define Mq (Bq*Sq)        // 12544
#define KHEADq (Sq*Dq)    // 50176
#define STq 3072          // fused qkv row stride

typedef unsigned short u16;
typedef short bf16x8 __attribute__((ext_vector_type(8)));
typedef float f32x4 __attribute__((ext_vector_type(4)));

__device__ inline u16 f2bf(float f){
  union { float f; uint32_t u; } c; c.f = f;
  uint32_t r = c.u + 0x7FFFu + ((c.u >> 16) & 1u);
  return (u16)(r >> 16);
}

#define GLOAD_LDS16(gp, lp) \
  __builtin_amdgcn_global_load_lds((__attribute__((address_space(1))) void*)(gp), \
                                   (__attribute__((address_space(3))) void*)(lp), 16, 0, 0)
#define MFMA16(a,b,c) __builtin_amdgcn_mfma_f32_16x16x32_bf16(a,b,c,0,0,0)

// h[b*49+s][c] = x[b][c][s] + pos[s][c]  -- LDS transpose for coalescing
__global__ __launch_bounds__(256) void prep_kernel(const float* __restrict__ x,
    const float* __restrict__ pos, float* __restrict__ h){
  __shared__ float t[49*129];
  int b = blockIdx.x, c0 = blockIdx.y*128;
  int tid = threadIdx.x, lane = tid & 63, wave = tid >> 6;
  const float* xb = x + (size_t)b*(Dq*Sq) + (size_t)c0*Sq;
  #pragma unroll
  for(int i=0;i<32;i++){
    int cc = wave + i*4;
    if(lane < Sq) t[lane*129 + cc] = xb[(size_t)cc*Sq + lane];
  }
  __syncthreads();
  #pragma unroll
  for(int p=0;p<25;p++){
    int idx = p*256 + tid;
    int s = idx >> 7, cc = idx & 127;
    if(s < Sq)
      h[((size_t)b*Sq + s)*Dq + c0 + cc] = t[s*129 + cc] + pos[s*Dq + c0 + cc];
  }
}

// LayerNorm over D=1024, one wave per row, bf16 output
__global__ __launch_bounds__(256) void ln_kernel(const float* __restrict__ hin,
    const float* __restrict__ sc, const float* __restrict__ bi, u16* __restrict__ outp){
  int wave = threadIdx.x >> 6, lane = threadIdx.x & 63;
  int row = blockIdx.x*4 + wave;
  const float* p = hin + (size_t)row*Dq + lane*16;
  float v[16];
  #pragma unroll
  for(int i=0;i<4;i++){
    f32x4 t = *(const f32x4*)(p + i*4);
    v[4*i]=t[0]; v[4*i+1]=t[1]; v[4*i+2]=t[2]; v[4*i+3]=t[3];
  }
  float s=0.f, sq=0.f;
  #pragma unroll
  for(int i=0;i<16;i++){ s += v[i]; sq += v[i]*v[i]; }
  #pragma unroll
  for(int o=32;o>=1;o>>=1){ s += __shfl_xor(s,o); sq += __shfl_xor(sq,o); }
  float mean = s * (1.f/Dq);
  float var  = sq * (1.f/Dq) - mean*mean;
  float rs = rsqrtf(var + 1e-5f);
  int c0 = lane*16;
  uint32_t w[8];
  #pragma unroll
  for(int i=0;i<8;i++){
    u16 lo = f2bf((v[2*i]   - mean)*rs*sc[c0+2*i]   + bi[c0+2*i]);
    u16 hi = f2bf((v[2*i+1] - mean)*rs*sc[c0+2*i+1] + bi[c0+2*i+1]);
    w[i] = (uint32_t)lo | ((uint32_t)hi << 16);
  }
  uint4* ob = (uint4*)(outp + (size_t)row*Dq + c0);
  ob[0] = make_uint4(w[0],w[1],w[2],w[3]);
  ob[1] = make_uint4(w[4],w[5],w[6],w[7]);
}

// all 12 layer weights: (K=1024,N=1024) f32 -> (N,K) bf16, slot = blockIdx.z
__global__ void transp_all(const float* __restrict__ wq, const float* __restrict__ wk,
    const float* __restrict__ wv, const float* __restrict__ wo,
    const float* __restrict__ w1, const float* __restrict__ w2, u16* __restrict__ outp){
  __shared__ float t[32][33];
  int slot = blockIdx.z; int l = slot / 6, j = slot - l*6;
  const float* srcs[6] = {wq,wk,wv,wo,w1,w2};
  const float* in = srcs[j] + (size_t)l*Dq*Dq;
  u16* o = outp + (size_t)slot*Dq*Dq;
  int k0 = blockIdx.x*32, n0 = blockIdx.y*32;
  int tx = threadIdx.x, ty = threadIdx.y;
  #pragma unroll
  for(int i=0;i<4;i++) t[ty+8*i][tx] = in[(size_t)(k0+ty+8*i)*Dq + n0+tx];
  __syncthreads();
  #pragma unroll
  for(int i=0;i<4;i++) o[(size_t)(n0+ty+8*i)*Dq + k0+tx] = f2bf(t[tx][ty+8*i]);
}

// ================= 256x256 8-wave phase-scheduled NT GEMM (K=1024) =================
// C[m][n] = sum_k A[m][k]*Bt[n][k]; A,Bt bf16 K-contiguous. BK=64, nk=16 K-tiles,
// double-buffered LDS with XOR swizzle (byte ^= (row&7)<<4) on both stage-source
// and ds_read; 4 phases/tile x 16 MFMA; counted vmcnt(2) at tile boundaries only.
// EPI: 0 = bf16 out; 1 = f32 out = resid + acc (+bias); 2 = bf16 out = gelu(acc+bias)
template<int EPI>
__global__ __launch_bounds__(512, 2) void gemm_nt2(
    const u16* __restrict__ A, int lda,
    const u16* __restrict__ Bt, int ldb,
    void* __restrict__ Cout, const float* __restrict__ resid,
    const float* __restrict__ bias, int ldc)
{
  __shared__ u16 lds[65536];   // [A d=0 |A d=1 | B d=0 | B d=1], 16384 u16 each
  int tid = threadIdx.x, lane = tid & 63;
  int wave = tid >> 6;
  int wm = wave >> 2, wn = wave & 3;
  int l15 = lane & 15, l4 = lane >> 4;
  int swz = (l15 & 7) << 4;

  // bijective XCD chunk swizzle (m204)
  int gx = gridDim.x, nwg = gx*gridDim.y;
  int orig = blockIdx.y*gx + blockIdx.x;
  int qq = nwg >> 3, rr = nwg & 7;
  int xcd = orig & 7, idx = orig >> 3;
  int wgid = (xcd < rr ? xcd*(qq+1) : rr*(qq+1) + (xcd-rr)*qq) + idx;
  int bx = wgid % gx, by = wgid / gx;
  int m0 = by*256, n0 = bx*256;

  // staging: 8 loads/tile; load c: row=c*64+(tid>>3), colb=(tid&7)*16 (c<4:A, else B)
  int srow = tid >> 3, scolb = (tid & 7) * 16;
  int scolx = scolb ^ ((srow & 7) << 4);          // (row&7)==((tid>>3)&7) for all c
  auto stage2 = [&](int d, int kt, int h){
    #pragma unroll
    for(int cc=0; cc<2; cc++){
      int c = 2*h + cc;
      if(c < 4){
        int row = c*64 + srow;
        const u16* src = A + (size_t)(m0+row)*lda + kt*64 + (scolx>>1);
        GLOAD_LDS16(src, &lds[d*16384 + c*4096 + tid*8]);
      } else {
        int c4 = c - 4;
        int row = c4*64 + srow;
        const u16* src = Bt + (size_t)(n0+row)*ldb + kt*64 + (scolx>>1);
        GLOAD_LDS16(src, &lds[32768 + d*16384 + c4*4096 + tid*8]);
      }
    }
  };
  auto rdA = [&](int d, int i, int s)->bf16x8{
    int row = wm*128 + i*16 + l15;
    int byt = row*128 + ((s*64 + l4*16) ^ swz);
    return *(const bf16x8*)((const char*)lds + d*32768 + byt);
  };
  auto rdB = [&](int d, int n, int s)->bf16x8{
    int row = wn*64 + n*16 + l15;
    int byt = row*128 + ((s*64 + l4*16) ^ swz);
    return *(const bf16x8*)((const char*)lds + 65536 + d*32768 + byt);
  };

  f32x4 acc[8][4] = {};
  bf16x8 bfr[4][2];

  // prologue: stage tile 0 fully
  #pragma unroll
  for(int h=0;h<4;h++) stage2(0, 0, h);

  for(int t=0; t<16; ++t){
    int d = t & 1;
    // ---- phase 0: guard tile t resident, read b-frags + quad0, 16 MFMA ----
    if(t+1 < 16){
      stage2(d^1, t+1, 0);
      asm volatile("s_waitcnt vmcnt(2)" ::: "memory");
    } else {
      asm volatile("s_waitcnt vmcnt(0)" ::: "memory");
    }
    __builtin_amdgcn_sched_barrier(0);
    __builtin_amdgcn_s_barrier();
    #pragma unroll
    for(int n=0;n<4;n++)
      #pragma unroll
      for(int s=0;s<2;s++)
        bfr[n][s] = rdB(d, n, s);
    {
      bf16x8 a00 = rdA(d,0,0), a01 = rdA(d,0,1), a10 = rdA(d,1,0), a11 = rdA(d,1,1);
      __builtin_amdgcn_s_setprio(1);
      #pragma unroll
      for(int n=0;n<4;n++){
        acc[0][n] = MFMA16(a00, bfr[n][0], acc[0][n]);
        acc[0][n] = MFMA16(a01, bfr[n][1], acc[0][n]);
        acc[1][n] = MFMA16(a10, bfr[n][0], acc[1][n]);
        acc[1][n] = MFMA16(a11, bfr[n][1], acc[1][n]);
      }
      __builtin_amdgcn_s_setprio(0);
      __builtin_amdgcn_s_barrier();
    }
    // ---- phases 1..3 ----
    #pragma unroll
    for(int q=1;q<4;q++){
      bf16x8 a00 = rdA(d,2*q,0), a01 = rdA(d,2*q,1), a10 = rdA(d,2*q+1,0), a11 = rdA(d,2*q+1,1);
      if(t+1 < 16) stage2(d^1, t+1, q);
      __builtin_amdgcn_s_barrier();
      __builtin_amdgcn_s_setprio(1);
      #pragma unroll
      for(int n=0;n<4;n++){
        acc[2*q][n]   = MFMA16(a00, bfr[n][0], acc[2*q][n]);
        acc[2*q][n]   = MFMA16(a01, bfr[n][1], acc[2*q][n]);
        acc[2*q+1][n] = MFMA16(a10, bfr[n][0], acc[2*q+1][n]);
        acc[2*q+1][n] = MFMA16(a11, bfr[n][1], acc[2*q+1][n]);
      }
      __builtin_amdgcn_s_setprio(0);
      __builtin_amdgcn_s_barrier();
    }
  }

  // ---- epilogue (all LDS free after final barrier) ----
  if constexpr (EPI == 1){
    float* slot = (float*)((char*)lds + wave*4096);   // 16x64 f32
    float bv[4];
    #pragma unroll
    for(int n=0;n<4;n++) bv[n] = bias ? bias[n0 + wn*64 + n*16 + l15] : 0.f;
    #pragma unroll
    for(int i=0;i<8;i++){
      #pragma unroll
      for(int n=0;n<4;n++)
        #pragma unroll
        for(int r=0;r<4;r++)
          slot[(l4*4+r)*64 + n*16 + l15] = acc[i][n][r] + bv[n];
      #pragma unroll
      for(int st=0;st<4;st++){
        int u = st*64 + lane;
        int row = u >> 4, c4 = (u & 15)*4;
        f32x4 v4 = *(const f32x4*)&slot[row*64 + c4];
        size_t o = (size_t)(m0 + wm*128 + i*16 + row)*ldc + n0 + wn*64 + c4;
        f32x4 r4 = *(const f32x4*)&resid[o];
        *(f32x4*)((float*)Cout + o) = v4 + r4;
      }
    }
  } else {
    u16* slot = (u16*)((char*)lds + wave*2048);       // 16x64 bf16
    float bv[4];
    if constexpr (EPI == 2){
      #pragma unroll
      for(int n=0;n<4;n++) bv[n] = bias[n0 + wn*64 + n*16 + l15];
    }
    #pragma unroll
    for(int i=0;i<8;i++){
      #pragma unroll
      for(int n=0;n<4;n++)
        #pragma unroll
        for(int r=0;r<4;r++){
          float va = acc[i][n][r];
          u16 ov;
          if constexpr (EPI == 0){
            ov = f2bf(va);
          } else {
            float xg = va + bv[n];
            float tg = tanhf(0.79788456080286536f*(xg + 0.044715f*xg*xg*xg));
            ov = f2bf(0.5f*xg*(1.f+tg));
          }
          slot[(l4*4+r)*64 + n*16 + l15] = ov;
        }
      #pragma unroll
      for(int st=0;st<2;st++){
        int u = st*64 + lane;
        int row = u >> 3, c8 = (u & 7)*8;
        bf16x8 v8 = *(const bf16x8*)&slot[row*64 + c8];
        *(bf16x8*)((u16*)Cout + (size_t)(m0 + wm*128 + i*16 + row)*ldc + n0 + wn*64 + c8) = v8;
      }
    }
  }
}

// Head GEMM: A (256,50176) bf16 K-contig; W (50176,1024) f32 N-contig (reg-converted).
// Split-K by s: z = 0..48, klen=1024. parts[49][256][1024] f32, LDS-staged stores.
__global__ __launch_bounds__(256) void gemm_head(
    const u16* __restrict__ A, const float* __restrict__ W,
    float* __restrict__ parts)
{
  __shared__ u16 sA[128*32];
  __shared__ float sC[4][1024];
  int tid = threadIdx.x, lane = tid & 63;
  int wave = tid >> 6;
  int wm = wave >> 1, wn = wave & 1;
  int l15 = lane & 15, l4 = lane >> 4;
  int nwg = gridDim.x*gridDim.y*gridDim.z;
  int orig = (blockIdx.z*gridDim.y + blockIdx.y)*gridDim.x + blockIdx.x;
  int cpx = nwg >> 3;
  int swz = (orig & 7)*cpx + (orig >> 3);
  int bx = swz & 7, by = (swz >> 3) & 1, z = swz >> 4;
  int m0 = by*128, n0 = bx*128;
  size_t abase = (size_t)m0*KHEADq + (size_t)z*1024;
  f32x4 acc[4][4] = {};
  const float* wp = W + ((size_t)z*1024 + (size_t)l4*8)*1024 + n0 + wn*64 + l15;
  for(int kt=0;kt<32;kt++){
    #pragma unroll
    for(int c=0;c<2;c++){
      int s2 = c*256+tid;
      GLOAD_LDS16(A + abase + (size_t)(s2>>2)*KHEADq + kt*32 + (s2&3)*8, &sA[s2*8]);
    }
    float wreg[4][8];
    #pragma unroll
    for(int f=0;f<4;f++)
      #pragma unroll
      for(int jj=0;jj<8;jj++)
        wreg[f][jj] = wp[(size_t)(kt*32+jj)*1024 + f*16];
    bf16x8 bfr[4];
    #pragma unroll
    for(int f=0;f<4;f++){
      bf16x8 bv;
      #pragma unroll
      for(int jj=0;jj<8;jj++)
        bv[jj] = __builtin_bit_cast(short, __float2bfloat16(wreg[f][jj]));
      bfr[f] = bv;
    }
    __syncthreads();
    bf16x8 af[4];
    #pragma unroll
    for(int f=0;f<4;f++)
      af[f] = *(const bf16x8*)&sA[(wm*64 + f*16 + l15)*32 + l4*8];
    #pragma unroll
    for(int i=0;i<4;i++)
      #pragma unroll
      for(int j=0;j<4;j++)
        acc[i][j] = MFMA16(af[i], bfr[j], acc[i][j]);
    __syncthreads();
  }
  float* base = parts + (size_t)z*(Bq*1024);
  #pragma unroll
  for(int i=0;i<4;i++){
    #pragma unroll
    for(int j=0;j<4;j++)
      #pragma unroll
      for(int r=0;r<4;r++)
        sC[wave][(l4*4+r)*64 + j*16 + l15] = acc[i][j][r];
    #pragma unroll
    for(int st=0;st<4;st++){
      int u = st*64 + lane;
      int row = u >> 4, c4 = (u & 15)*4;
      f32x4 v4 = *(const f32x4*)&sC[wave][row*64 + c4];
      *(f32x4*)(base + (size_t)(m0+wm*64+i*16+row)*1024 + n0+wn*64+c4) = v4;
    }
  }
}

// Fused attention per (b,h) on the fused qkv buffer (row stride 3072).
__global__ __launch_bounds__(256) void attn_kernel(u16* __restrict__ qkv)
{
  __shared__ float sS[64][65];
  __shared__ u16 sP[64][64];
  int bh = blockIdx.x;
  int b = bh >> 1, h = bh & 1;
  int tid = threadIdx.x, lane = tid & 63, wave = tid >> 6;
  int l15 = lane & 15, l4 = lane >> 4;
  f32x4 zero4 = {0.f,0.f,0.f,0.f};
  bf16x8 zb = {0,0,0,0,0,0,0,0};
  f32x4 acc[4];
  #pragma unroll
  for(int i=0;i<4;i++) acc[i] = zero4;
  int srow = wave*16 + l15;
  const u16* qp = qkv + (size_t)(b*Sq + srow)*STq + h*HDq + l4*8;
  const u16* kbase = qkv + (size_t)b*Sq*STq + Dq + h*HDq + l4*8;
  for(int kt=0;kt<16;kt++){
    bf16x8 aq = (srow < Sq) ? *(const bf16x8*)(qp + kt*32) : zb;
    #pragma unroll
    for(int fn=0;fn<4;fn++){
      int s2 = fn*16 + l15;
      bf16x8 bk = (s2 < Sq) ? *(const bf16x8*)(kbase + (size_t)s2*STq + kt*32) : zb;
      acc[fn] = MFMA16(aq, bk, acc[fn]);
    }
  }
  const float scale = 0.04419417382415922f; // 1/sqrt(512)
  #pragma unroll
  for(int fn=0;fn<4;fn++)
    #pragma unroll
    for(int r=0;r<4;r++)
      sS[wave*16 + l4*4 + r][fn*16 + l15] = acc[fn][r]*scale;
  __syncthreads();
  if(tid < 64){
    float mx = -1e30f;
    for(int j=0;j<Sq;j++) mx = fmaxf(mx, sS[tid][j]);
    float sum = 0.f;
    for(int j=0;j<Sq;j++){ float e = __expf(sS[tid][j]-mx); sS[tid][j]=e; sum+=e; }
    float inv = 1.f/sum;
    for(int j=0;j<64;j++) sP[tid][j] = (j<Sq)? f2bf(sS[tid][j]*inv) : (u16)0;
  }
  __syncthreads();
  bf16x8 ap[2];
  #pragma unroll
  for(int kt2=0;kt2<2;kt2++)
    ap[kt2] = *(const bf16x8*)&sP[wave*16 + l15][kt2*32 + l4*8];
  const u16* vbp = qkv + (size_t)b*Sq*STq + 2*Dq + h*HDq + l15;
  u16* cb = qkv + (size_t)b*Sq*STq + h*HDq;
  for(int fn=0;fn<32;fn++){
    f32x4 c4 = zero4;
    #pragma unroll
    for(int kt2=0;kt2<2;kt2++){
      const u16* vp = vbp + fn*16 + (size_t)(kt2*32 + l4*8)*STq;
      bf16x8 bv;
      #pragma unroll
      for(int jj=0;jj<8;jj++) bv[jj] = (short)vp[(size_t)jj*STq];
      c4 = MFMA16(ap[kt2], bv, c4);
    }
    #pragma unroll
    for(int r=0;r<4;r++){
      int s = wave*16 + l4*4 + r;
      if(s < Sq) cb[(size_t)s*STq + fn*16 + l15] = f2bf(c4[r]);
    }
  }
}

__global__ __launch_bounds__(256) void head_finalize(const float* __restrict__ parts,
    const float* __restrict__ hb, float* __restrict__ outp){
  int idx = blockIdx.x*256 + threadIdx.x;
  float s = hb[idx & 1023];
  #pragma unroll
  for(int z=0;z<49;z++) s += parts[(size_t)z*(Bq*1024) + idx];
  outp[idx] = fmaxf(s, 0.f);
}

extern "C" void kernel_launch(void* const* d_in, const int* in_sizes, int n_in,
                              void* d_out, int out_size, void* d_ws, size_t ws_size,
                              hipStream_t stream) {
  (void)in_sizes; (void)n_in; (void)out_size;
  const float* x    = (const float*)d_in[0];
  const float* pos  = (const float*)d_in[1];
  const float* ln1s = (const float*)d_in[2];
  const float* ln1b = (const float*)d_in[3];
  const float* wq   = (const float*)d_in[4];
  const float* wk   = (const float*)d_in[5];
  const float* wv   = (const float*)d_in[6];
  const float* wo   = (const float*)d_in[7];
  const float* ln2s = (const float*)d_in[8];
  const float* ln2b = (const float*)d_in[9];
  const float* w1   = (const float*)d_in[10];
  const float* b1   = (const float*)d_in[11];
  const float* w2   = (const float*)d_in[12];
  const float* b2   = (const float*)d_in[13];
  const float* lnfs = (const float*)d_in[14];
  const float* lnfb = (const float*)d_in[15];
  const float* hw   = (const float*)d_in[16];
  const float* hb   = (const float*)d_in[17];
  float* out = (float*)d_out;

  char* ws = (char*)d_ws;
  size_t off = 0;
  auto carve = [&](size_t n) -> char* { char* p = ws + off; off += (n + 255) & ~(size_t)255; return p; };
  float* h    = (float*)carve((size_t)Mq*Dq*4);
  u16*  act0  = (u16*) carve((size_t)Mq*Dq*2);
  u16*  act1  = (u16*) carve((size_t)Mq*Dq*2);
  u16*  qkv   = (u16*) carve((size_t)(Mq+16)*STq*2);
  u16*  wT    = (u16*) carve((size_t)12*Dq*Dq*2);
  float* parts= (float*)qkv;  // head partials alias qkv (dead by head time)
  if (off > ws_size) return;

  // zero qkv pad rows (attention PV reads v-pad rows against P=0; must be finite)
  hipMemsetAsync(qkv + (size_t)Mq*STq, 0, (size_t)16*STq*2, stream);

  prep_kernel<<<dim3(Bq, 8), 256, 0, stream>>>(x, pos, h);
  transp_all<<<dim3(32,32,12), dim3(32,8), 0, stream>>>(wq, wk, wv, wo, w1, w2, wT);

  dim3 gg(4, Mq/256);    // N=1024 gemms: 4x49
  dim3 gq(12, Mq/256);   // qkv gemm: 12x49
  for(int l=0;l<2;l++){
    u16* qkvT = wT + (size_t)(l*6+0)*Dq*Dq;  // q,k,v slots contiguous -> 3072 x 1024
    u16* woT  = wT + (size_t)(l*6+3)*Dq*Dq;
    u16* w1T  = wT + (size_t)(l*6+4)*Dq*Dq;
    u16* w2T  = wT + (size_t)(l*6+5)*Dq*Dq;

    ln_kernel<<<Mq/4, 256, 0, stream>>>(h, ln1s + l*Dq, ln1b + l*Dq, act0);
    gemm_nt2<0><<<gq, 512, 0, stream>>>(act0, Dq, qkvT, Dq, qkv, nullptr, nullptr, STq);
    attn_kernel<<<Bq*Hq, 256, 0, stream>>>(qkv);
    gemm_nt2<1><<<gg, 512, 0, stream>>>(qkv, STq, woT, Dq, h, h, nullptr, Dq);
    ln_kernel<<<Mq/4, 256, 0, stream>>>(h, ln2s + l*Dq, ln2b + l*Dq, act0);
    gemm_nt2<2><<<gg, 512, 0, stream>>>(act0, Dq, w1T, Dq, act1, nullptr, b1 + l*Dq, Dq);
    gemm_nt2<1><<<gg, 512, 0, stream>>>(act1, Dq, w2T, Dq, h, h, b2 + l*Dq, Dq);
  }

  ln_kernel<<<Mq/4, 256, 0, stream>>>(h, lnfs, lnfb, act0);
  gemm_head<<<dim3(8,2,49), 256, 0, stream>>>(act0, hw, parts);
  head_finalize<<<1024, 256, 0, stream>>>(parts, hb, out);
}

// Round 5
// 683.578 us; speedup vs baseline: 1.7780x; 1.0798x over previous
//
#include <hip/hip_runtime.h>
#include <hip/hip_bf16.h>
#include <stdint.h>

#define Bq 256
#define Sq 49
#define Dq 1024
#define Hq 2
#define HDq 512
#define Mq (Bq*Sq)        // 12544
#define KHEADq (Sq*Dq)    // 50176
#define STq 3072          // fused qkv row stride

typedef unsigned short u16;
typedef short bf16x8 __attribute__((ext_vector_type(8)));
typedef float f32x4 __attribute__((ext_vector_type(4)));

__device__ inline u16 f2bf(float f){
  union { float f; uint32_t u; } c; c.f = f;
  uint32_t r = c.u + 0x7FFFu + ((c.u >> 16) & 1u);
  return (u16)(r >> 16);
}
__device__ inline float bf2f(u16 h){
  union { uint32_t u; float f; } c; c.u = ((uint32_t)h) << 16;
  return c.f;
}

#define GLOAD_LDS16(gp, lp) \
  __builtin_amdgcn_global_load_lds((__attribute__((address_space(1))) void*)(gp), \
                                   (__attribute__((address_space(3))) void*)(lp), 16, 0, 0)
#define MFMA16(a,b,c) __builtin_amdgcn_mfma_f32_16x16x32_bf16(a,b,c,0,0,0)

// h[b*49+s][c] = bf16(x[b][c][s] + pos[s][c])  -- LDS transpose for coalescing
__global__ __launch_bounds__(256) void prep_kernel(const float* __restrict__ x,
    const float* __restrict__ pos, u16* __restrict__ h){
  __shared__ float t[49*129];
  int b = blockIdx.x, c0 = blockIdx.y*128;
  int tid = threadIdx.x, lane = tid & 63, wave = tid >> 6;
  const float* xb = x + (size_t)b*(Dq*Sq) + (size_t)c0*Sq;
  #pragma unroll
  for(int i=0;i<32;i++){
    int cc = wave + i*4;
    if(lane < Sq) t[lane*129 + cc] = xb[(size_t)cc*Sq + lane];
  }
  __syncthreads();
  #pragma unroll
  for(int p=0;p<25;p++){
    int idx = p*256 + tid;
    int s = idx >> 7, cc = idx & 127;
    if(s < Sq)
      h[((size_t)b*Sq + s)*Dq + c0 + cc] = f2bf(t[s*129 + cc] + pos[s*Dq + c0 + cc]);
  }
}

// LayerNorm over D=1024, one wave per row, bf16 in (residual stream), bf16 out
__global__ __launch_bounds__(256) void ln_kernel(const u16* __restrict__ hin,
    const float* __restrict__ sc, const float* __restrict__ bi, u16* __restrict__ outp){
  int wave = threadIdx.x >> 6, lane = threadIdx.x & 63;
  int row = blockIdx.x*4 + wave;
  const u16* p = hin + (size_t)row*Dq + lane*16;
  uint4 t0 = *(const uint4*)p;
  uint4 t1 = *(const uint4*)(p + 8);
  float v[16];
  {
    uint32_t wds[8] = {t0.x,t0.y,t0.z,t0.w,t1.x,t1.y,t1.z,t1.w};
    #pragma unroll
    for(int i=0;i<8;i++){
      v[2*i]   = bf2f((u16)(wds[i] & 0xffff));
      v[2*i+1] = bf2f((u16)(wds[i] >> 16));
    }
  }
  float s=0.f, sq=0.f;
  #pragma unroll
  for(int i=0;i<16;i++){ s += v[i]; sq += v[i]*v[i]; }
  #pragma unroll
  for(int o=32;o>=1;o>>=1){ s += __shfl_xor(s,o); sq += __shfl_xor(sq,o); }
  float mean = s * (1.f/Dq);
  float var  = sq * (1.f/Dq) - mean*mean;
  float rs = rsqrtf(var + 1e-5f);
  int c0 = lane*16;
  uint32_t w[8];
  #pragma unroll
  for(int i=0;i<8;i++){
    u16 lo = f2bf((v[2*i]   - mean)*rs*sc[c0+2*i]   + bi[c0+2*i]);
    u16 hi = f2bf((v[2*i+1] - mean)*rs*sc[c0+2*i+1] + bi[c0+2*i+1]);
    w[i] = (uint32_t)lo | ((uint32_t)hi << 16);
  }
  uint4* ob = (uint4*)(outp + (size_t)row*Dq + c0);
  ob[0] = make_uint4(w[0],w[1],w[2],w[3]);
  ob[1] = make_uint4(w[4],w[5],w[6],w[7]);
}

// all 12 layer weights: (K=1024,N=1024) f32 -> (N,K) bf16, slot = blockIdx.z
__global__ void transp_all(const float* __restrict__ wq, const float* __restrict__ wk,
    const float* __restrict__ wv, const float* __restrict__ wo,
    const float* __restrict__ w1, const float* __restrict__ w2, u16* __restrict__ outp){
  __shared__ float t[32][33];
  int slot = blockIdx.z; int l = slot / 6, j = slot - l*6;
  const float* srcs[6] = {wq,wk,wv,wo,w1,w2};
  const float* in = srcs[j] + (size_t)l*Dq*Dq;
  u16* o = outp + (size_t)slot*Dq*Dq;
  int k0 = blockIdx.x*32, n0 = blockIdx.y*32;
  int tx = threadIdx.x, ty = threadIdx.y;
  #pragma unroll
  for(int i=0;i<4;i++) t[ty+8*i][tx] = in[(size_t)(k0+ty+8*i)*Dq + n0+tx];
  __syncthreads();
  #pragma unroll
  for(int i=0;i<4;i++) o[(size_t)(n0+ty+8*i)*Dq + k0+tx] = f2bf(t[tx][ty+8*i]);
}

// ================= 256x256 8-wave 5-phase NT GEMM (K=1024) =================
// BK=64, 16 K-tiles, double-buffered XOR-swizzled LDS; phases balanced to <=8
// ds_read_b128 each; counted vmcnt(2) at tile boundary only.
// EPI: 0 = bf16 out; 1 = bf16 out = resid(bf16) + acc (+bias); 2 = bf16 gelu(acc+bias)
template<int EPI>
__global__ __launch_bounds__(512, 2) void gemm_nt2(
    const u16* __restrict__ A, int lda,
    const u16* __restrict__ Bt, int ldb,
    void* __restrict__ Cout, const u16* __restrict__ resid,
    const float* __restrict__ bias, int ldc)
{
  __shared__ u16 lds[65536];   // A: 2x16K u16, B: 2x16K u16
  int tid = threadIdx.x, lane = tid & 63;
  int wave = tid >> 6;
  int wm = wave >> 2, wn = wave & 3;
  int l15 = lane & 15, l4 = lane >> 4;
  int swz = (l15 & 7) << 4;

  // bijective XCD chunk swizzle (m204)
  int gx = gridDim.x, nwg = gx*gridDim.y;
  int orig = blockIdx.y*gx + blockIdx.x;
  int qq = nwg >> 3, rr = nwg & 7;
  int xcd = orig & 7, idx = orig >> 3;
  int wgid = (xcd < rr ? xcd*(qq+1) : rr*(qq+1) + (xcd-rr)*qq) + idx;
  int bx = wgid % gx, by = wgid / gx;
  int m0 = by*256, n0 = bx*256;

  int srow = tid >> 3, scolb = (tid & 7) * 16;
  int scolx = scolb ^ ((srow & 7) << 4);
  auto stage2 = [&](int d, int kt, int h){
    #pragma unroll
    for(int cc=0; cc<2; cc++){
      int c = 2*h + cc;
      if(c < 4){
        int row = c*64 + srow;
        const u16* src = A + (size_t)(m0+row)*lda + kt*64 + (scolx>>1);
        GLOAD_LDS16(src, &lds[d*16384 + c*4096 + tid*8]);
      } else {
        int c4 = c - 4;
        int row = c4*64 + srow;
        const u16* src = Bt + (size_t)(n0+row)*ldb + kt*64 + (scolx>>1);
        GLOAD_LDS16(src, &lds[32768 + d*16384 + c4*4096 + tid*8]);
      }
    }
  };
  auto rdA = [&](int d, int i, int s)->bf16x8{
    int row = wm*128 + i*16 + l15;
    int byt = row*128 + ((s*64 + l4*16) ^ swz);
    return *(const bf16x8*)((const char*)lds + d*32768 + byt);
  };
  auto rdB = [&](int d, int n, int s)->bf16x8{
    int row = wn*64 + n*16 + l15;
    int byt = row*128 + ((s*64 + l4*16) ^ swz);
    return *(const bf16x8*)((const char*)lds + 65536 + d*32768 + byt);
  };

  f32x4 acc[8][4] = {};

  // prologue: stage tile 0 fully
  #pragma unroll
  for(int h=0;h<4;h++) stage2(0, 0, h);

  for(int t=0; t<16; ++t){
    int d = t & 1;
    bf16x8 bfr[4][2];
    // ---- P0: tile-boundary wait; B[0..1], A[0..1]; 8 MFMA ----
    if(t < 15){
      stage2(d^1, t+1, 0);
      asm volatile("s_waitcnt vmcnt(2)" ::: "memory");
    } else {
      asm volatile("s_waitcnt vmcnt(0)" ::: "memory");
    }
    __builtin_amdgcn_sched_barrier(0);
    __builtin_amdgcn_s_barrier();
    bfr[0][0]=rdB(d,0,0); bfr[0][1]=rdB(d,0,1);
    bfr[1][0]=rdB(d,1,0); bfr[1][1]=rdB(d,1,1);
    bf16x8 a0s0=rdA(d,0,0), a0s1=rdA(d,0,1), a1s0=rdA(d,1,0), a1s1=rdA(d,1,1);
    __builtin_amdgcn_s_setprio(1);
    acc[0][0]=MFMA16(a0s0,bfr[0][0],acc[0][0]); acc[0][0]=MFMA16(a0s1,bfr[0][1],acc[0][0]);
    acc[0][1]=MFMA16(a0s0,bfr[1][0],acc[0][1]); acc[0][1]=MFMA16(a0s1,bfr[1][1],acc[0][1]);
    acc[1][0]=MFMA16(a1s0,bfr[0][0],acc[1][0]); acc[1][0]=MFMA16(a1s1,bfr[0][1],acc[1][0]);
    acc[1][1]=MFMA16(a1s0,bfr[1][0],acc[1][1]); acc[1][1]=MFMA16(a1s1,bfr[1][1],acc[1][1]);
    __builtin_amdgcn_s_setprio(0);
    __builtin_amdgcn_s_barrier();
    // ---- P1: B[2..3]; 8 MFMA (A[0..1] kept in regs) ----
    bfr[2][0]=rdB(d,2,0); bfr[2][1]=rdB(d,2,1);
    bfr[3][0]=rdB(d,3,0); bfr[3][1]=rdB(d,3,1);
    if(t < 15) stage2(d^1, t+1, 1);
    __builtin_amdgcn_s_barrier();
    __builtin_amdgcn_s_setprio(1);
    acc[0][2]=MFMA16(a0s0,bfr[2][0],acc[0][2]); acc[0][2]=MFMA16(a0s1,bfr[2][1],acc[0][2]);
    acc[0][3]=MFMA16(a0s0,bfr[3][0],acc[0][3]); acc[0][3]=MFMA16(a0s1,bfr[3][1],acc[0][3]);
    acc[1][2]=MFMA16(a1s0,bfr[2][0],acc[1][2]); acc[1][2]=MFMA16(a1s1,bfr[2][1],acc[1][2]);
    acc[1][3]=MFMA16(a1s0,bfr[3][0],acc[1][3]); acc[1][3]=MFMA16(a1s1,bfr[3][1],acc[1][3]);
    __builtin_amdgcn_s_setprio(0);
    __builtin_amdgcn_s_barrier();
    // ---- P2..P4: A-quads 2..7; 16 MFMA each ----
    #pragma unroll
    for(int q=1;q<4;q++){
      bf16x8 c0s0=rdA(d,2*q,0), c0s1=rdA(d,2*q,1), c1s0=rdA(d,2*q+1,0), c1s1=rdA(d,2*q+1,1);
      if(t < 15 && q < 3) stage2(d^1, t+1, q+1);
      __builtin_amdgcn_s_barrier();
      __builtin_amdgcn_s_setprio(1);
      #pragma unroll
      for(int n=0;n<4;n++){
        acc[2*q][n]   = MFMA16(c0s0, bfr[n][0], acc[2*q][n]);
        acc[2*q][n]   = MFMA16(c0s1, bfr[n][1], acc[2*q][n]);
        acc[2*q+1][n] = MFMA16(c1s0, bfr[n][0], acc[2*q+1][n]);
        acc[2*q+1][n] = MFMA16(c1s1, bfr[n][1], acc[2*q+1][n]);
      }
      __builtin_amdgcn_s_setprio(0);
      __builtin_amdgcn_s_barrier();
    }
  }

  // ---- epilogue (LDS free after final barrier) ----
  if constexpr (EPI == 1){
    float* slotf = (float*)((char*)lds + wave*4096);   // 16x64 f32
    float bv[4];
    #pragma unroll
    for(int n=0;n<4;n++) bv[n] = bias ? bias[n0 + wn*64 + n*16 + l15] : 0.f;
    #pragma unroll
    for(int i=0;i<8;i++){
      #pragma unroll
      for(int n=0;n<4;n++)
        #pragma unroll
        for(int r=0;r<4;r++)
          slotf[(l4*4+r)*64 + n*16 + l15] = acc[i][n][r] + bv[n];
      #pragma unroll
      for(int st=0;st<2;st++){
        int u = st*64 + lane;
        int row = u >> 3, c8 = (u & 7)*8;
        f32x4 lo = *(const f32x4*)&slotf[row*64 + c8];
        f32x4 hi = *(const f32x4*)&slotf[row*64 + c8 + 4];
        size_t o = (size_t)(m0 + wm*128 + i*16 + row)*ldc + n0 + wn*64 + c8;
        bf16x8 rb = *(const bf16x8*)(resid + o);
        bf16x8 ov;
        #pragma unroll
        for(int j=0;j<4;j++){
          ov[j]   = (short)f2bf(lo[j] + bf2f((u16)rb[j]));
          ov[4+j] = (short)f2bf(hi[j] + bf2f((u16)rb[4+j]));
        }
        *(bf16x8*)((u16*)Cout + o) = ov;
      }
    }
  } else {
    u16* slot = (u16*)((char*)lds + wave*2048);       // 16x64 bf16
    float bv[4];
    if constexpr (EPI == 2){
      #pragma unroll
      for(int n=0;n<4;n++) bv[n] = bias[n0 + wn*64 + n*16 + l15];
    }
    #pragma unroll
    for(int i=0;i<8;i++){
      #pragma unroll
      for(int n=0;n<4;n++)
        #pragma unroll
        for(int r=0;r<4;r++){
          float va = acc[i][n][r];
          u16 ov;
          if constexpr (EPI == 0){
            ov = f2bf(va);
          } else {
            float xg = va + bv[n];
            float tg = tanhf(0.79788456080286536f*(xg + 0.044715f*xg*xg*xg));
            ov = f2bf(0.5f*xg*(1.f+tg));
          }
          slot[(l4*4+r)*64 + n*16 + l15] = ov;
        }
      #pragma unroll
      for(int st=0;st<2;st++){
        int u = st*64 + lane;
        int row = u >> 3, c8 = (u & 7)*8;
        bf16x8 v8 = *(const bf16x8*)&slot[row*64 + c8];
        *(bf16x8*)((u16*)Cout + (size_t)(m0 + wm*128 + i*16 + row)*ldc + n0 + wn*64 + c8) = v8;
      }
    }
  }
}

// Head GEMM: A (256,50176) bf16 K-contig; W (50176,1024) f32 N-contig (reg-converted).
// Split-K by s: z = 0..48, klen=1024. parts[49][256][1024] f32, LDS-staged stores.
__global__ __launch_bounds__(256) void gemm_head(
    const u16* __restrict__ A, const float* __restrict__ W,
    float* __restrict__ parts)
{
  __shared__ u16 sA[128*32];
  __shared__ float sC[4][1024];
  int tid = threadIdx.x, lane = tid & 63;
  int wave = tid >> 6;
  int wm = wave >> 1, wn = wave & 1;
  int l15 = lane & 15, l4 = lane >> 4;
  int nwg = gridDim.x*gridDim.y*gridDim.z;
  int orig = (blockIdx.z*gridDim.y + blockIdx.y)*gridDim.x + blockIdx.x;
  int cpx = nwg >> 3;
  int swz = (orig & 7)*cpx + (orig >> 3);
  int bx = swz & 7, by = (swz >> 3) & 1, z = swz >> 4;
  int m0 = by*128, n0 = bx*128;
  size_t abase = (size_t)m0*KHEADq + (size_t)z*1024;
  f32x4 acc[4][4] = {};
  const float* wp = W + ((size_t)z*1024 + (size_t)l4*8)*1024 + n0 + wn*64 + l15;
  for(int kt=0;kt<32;kt++){
    #pragma unroll
    for(int c=0;c<2;c++){
      int s2 = c*256+tid;
      GLOAD_LDS16(A + abase + (size_t)(s2>>2)*KHEADq + kt*32 + (s2&3)*8, &sA[s2*8]);
    }
    float wreg[4][8];
    #pragma unroll
    for(int f=0;f<4;f++)
      #pragma unroll
      for(int jj=0;jj<8;jj++)
        wreg[f][jj] = wp[(size_t)(kt*32+jj)*1024 + f*16];
    bf16x8 bfr[4];
    #pragma unroll
    for(int f=0;f<4;f++){
      bf16x8 bv;
      #pragma unroll
      for(int jj=0;jj<8;jj++)
        bv[jj] = __builtin_bit_cast(short, __float2bfloat16(wreg[f][jj]));
      bfr[f] = bv;
    }
    __syncthreads();
    bf16x8 af[4];
    #pragma unroll
    for(int f=0;f<4;f++)
      af[f] = *(const bf16x8*)&sA[(wm*64 + f*16 + l15)*32 + l4*8];
    #pragma unroll
    for(int i=0;i<4;i++)
      #pragma unroll
      for(int j=0;j<4;j++)
        acc[i][j] = MFMA16(af[i], bfr[j], acc[i][j]);
    __syncthreads();
  }
  float* base = parts + (size_t)z*(Bq*1024);
  #pragma unroll
  for(int i=0;i<4;i++){
    #pragma unroll
    for(int j=0;j<4;j++)
      #pragma unroll
      for(int r=0;r<4;r++)
        sC[wave][(l4*4+r)*64 + j*16 + l15] = acc[i][j][r];
    #pragma unroll
    for(int st=0;st<4;st++){
      int u = st*64 + lane;
      int row = u >> 4, c4 = (u & 15)*4;
      f32x4 v4 = *(const f32x4*)&sC[wave][row*64 + c4];
      *(f32x4*)(base + (size_t)(m0+wm*64+i*16+row)*1024 + n0+wn*64+c4) = v4;
    }
  }
}

// Fused attention per (b,h) on the fused qkv buffer (row stride 3072).
__global__ __launch_bounds__(256) void attn_kernel(u16* __restrict__ qkv)
{
  __shared__ float sS[64][65];
  __shared__ u16 sP[64][64];
  int bh = blockIdx.x;
  int b = bh >> 1, h = bh & 1;
  int tid = threadIdx.x, lane = tid & 63, wave = tid >> 6;
  int l15 = lane & 15, l4 = lane >> 4;
  f32x4 zero4 = {0.f,0.f,0.f,0.f};
  bf16x8 zb = {0,0,0,0,0,0,0,0};
  f32x4 acc[4];
  #pragma unroll
  for(int i=0;i<4;i++) acc[i] = zero4;
  int srow = wave*16 + l15;
  const u16* qp = qkv + (size_t)(b*Sq + srow)*STq + h*HDq + l4*8;
  const u16* kbase = qkv + (size_t)b*Sq*STq + Dq + h*HDq + l4*8;
  for(int kt=0;kt<16;kt++){
    bf16x8 aq = (srow < Sq) ? *(const bf16x8*)(qp + kt*32) : zb;
    #pragma unroll
    for(int fn=0;fn<4;fn++){
      int s2 = fn*16 + l15;
      bf16x8 bk = (s2 < Sq) ? *(const bf16x8*)(kbase + (size_t)s2*STq + kt*32) : zb;
      acc[fn] = MFMA16(aq, bk, acc[fn]);
    }
  }
  const float scale = 0.04419417382415922f; // 1/sqrt(512)
  #pragma unroll
  for(int fn=0;fn<4;fn++)
    #pragma unroll
    for(int r=0;r<4;r++)
      sS[wave*16 + l4*4 + r][fn*16 + l15] = acc[fn][r]*scale;
  __syncthreads();
  if(tid < 64){
    float mx = -1e30f;
    for(int j=0;j<Sq;j++) mx = fmaxf(mx, sS[tid][j]);
    float sum = 0.f;
    for(int j=0;j<Sq;j++){ float e = __expf(sS[tid][j]-mx); sS[tid][j]=e; sum+=e; }
    float inv = 1.f/sum;
    for(int j=0;j<64;j++) sP[tid][j] = (j<Sq)? f2bf(sS[tid][j]*inv) : (u16)0;
  }
  __syncthreads();
  bf16x8 ap[2];
  #pragma unroll
  for(int kt2=0;kt2<2;kt2++)
    ap[kt2] = *(const bf16x8*)&sP[wave*16 + l15][kt2*32 + l4*8];
  const u16* vbp = qkv + (size_t)b*Sq*STq + 2*Dq + h*HDq + l15;
  u16* cb = qkv + (size_t)b*Sq*STq + h*HDq;
  for(int fn=0;fn<32;fn++){
    f32x4 c4 = zero4;
    #pragma unroll
    for(int kt2=0;kt2<2;kt2++){
      const u16* vp = vbp + fn*16 + (size_t)(kt2*32 + l4*8)*STq;
      bf16x8 bv;
      #pragma unroll
      for(int jj=0;jj<8;jj++) bv[jj] = (short)vp[(size_t)jj*STq];
      c4 = MFMA16(ap[kt2], bv, c4);
    }
    #pragma unroll
    for(int r=0;r<4;r++){
      int s = wave*16 + l4*4 + r;
      if(s < Sq) cb[(size_t)s*STq + fn*16 + l15] = f2bf(c4[r]);
    }
  }
}

__global__ __launch_bounds__(256) void head_finalize(const float* __restrict__ parts,
    const float* __restrict__ hb, float* __restrict__ outp){
  int idx = blockIdx.x*256 + threadIdx.x;
  float s = hb[idx & 1023];
  #pragma unroll
  for(int z=0;z<49;z++) s += parts[(size_t)z*(Bq*1024) + idx];
  outp[idx] = fmaxf(s, 0.f);
}

extern "C" void kernel_launch(void* const* d_in, const int* in_sizes, int n_in,
                              void* d_out, int out_size, void* d_ws, size_t ws_size,
                              hipStream_t stream) {
  (void)in_sizes; (void)n_in; (void)out_size;
  const float* x    = (const float*)d_in[0];
  const float* pos  = (const float*)d_in[1];
  const float* ln1s = (const float*)d_in[2];
  const float* ln1b = (const float*)d_in[3];
  const float* wq   = (const float*)d_in[4];
  const float* wk   = (const float*)d_in[5];
  const float* wv   = (const float*)d_in[6];
  const float* wo   = (const float*)d_in[7];
  const float* ln2s = (const float*)d_in[8];
  const float* ln2b = (const float*)d_in[9];
  const float* w1   = (const float*)d_in[10];
  const float* b1   = (const float*)d_in[11];
  const float* w2   = (const float*)d_in[12];
  const float* b2   = (const float*)d_in[13];
  const float* lnfs = (const float*)d_in[14];
  const float* lnfb = (const float*)d_in[15];
  const float* hw   = (const float*)d_in[16];
  const float* hb   = (const float*)d_in[17];
  float* out = (float*)d_out;

  char* ws = (char*)d_ws;
  size_t off = 0;
  auto carve = [&](size_t n) -> char* { char* p = ws + off; off += (n + 255) & ~(size_t)255; return p; };
  u16*  h     = (u16*) carve((size_t)Mq*Dq*2);      // residual stream, bf16
  u16*  act0  = (u16*) carve((size_t)Mq*Dq*2);
  u16*  act1  = (u16*) carve((size_t)Mq*Dq*2);
  u16*  qkv   = (u16*) carve((size_t)(Mq+16)*STq*2);
  u16*  wT    = (u16*) carve((size_t)12*Dq*Dq*2);
  float* parts= (float*)qkv;  // head partials alias qkv (dead by head time)
  if (off > ws_size) return;

  // zero qkv pad rows (attention PV reads v-pad rows against P=0; must be finite)
  hipMemsetAsync(qkv + (size_t)Mq*STq, 0, (size_t)16*STq*2, stream);

  prep_kernel<<<dim3(Bq, 8), 256, 0, stream>>>(x, pos, h);
  transp_all<<<dim3(32,32,12), dim3(32,8), 0, stream>>>(wq, wk, wv, wo, w1, w2, wT);

  dim3 gg(4, Mq/256);    // N=1024 gemms: 4x49
  dim3 gq(12, Mq/256);   // qkv gemm: 12x49
  for(int l=0;l<2;l++){
    u16* qkvT = wT + (size_t)(l*6+0)*Dq*Dq;  // q,k,v slots contiguous -> 3072 x 1024
    u16* woT  = wT + (size_t)(l*6+3)*Dq*Dq;
    u16* w1T  = wT + (size_t)(l*6+4)*Dq*Dq;
    u16* w2T  = wT + (size_t)(l*6+5)*Dq*Dq;

    ln_kernel<<<Mq/4, 256, 0, stream>>>(h, ln1s + l*Dq, ln1b + l*Dq, act0);
    gemm_nt2<0><<<gq, 512, 0, stream>>>(act0, Dq, qkvT, Dq, qkv, nullptr, nullptr, STq);
    attn_kernel<<<Bq*Hq, 256, 0, stream>>>(qkv);
    gemm_nt2<1><<<gg, 512, 0, stream>>>(qkv, STq, woT, Dq, h, h, nullptr, Dq);
    ln_kernel<<<Mq/4, 256, 0, stream>>>(h, ln2s + l*Dq, ln2b + l*Dq, act0);
    gemm_nt2<2><<<gg, 512, 0, stream>>>(act0, Dq, w1T, Dq, act1, nullptr, b1 + l*Dq, Dq);
    gemm_nt2<1><<<gg, 512, 0, stream>>>(act1, Dq, w2T, Dq, h, h, b2 + l*Dq, Dq);
  }

  ln_kernel<<<Mq/4, 256, 0, stream>>>(h, lnfs, lnfb, act0);
  gemm_head<<<dim3(8,2,49), 256, 0, stream>>>(act0, hw, parts);
  head_finalize<<<1024, 256, 0, stream>>>(parts, hb, out);
}